// Round 3
// baseline (919.466 us; speedup 1.0000x reference)
//
#include <hip/hip_runtime.h>

// ---------------- types / helpers ----------------
typedef __attribute__((ext_vector_type(8))) short bf16x8;   // 8 bf16 in 4 VGPRs (MFMA A/B frag)
typedef __attribute__((ext_vector_type(4))) float f32x4;    // MFMA C/D frag
typedef __attribute__((ext_vector_type(8))) unsigned short u16x8;

#define MFMA16(a, b, c) __builtin_amdgcn_mfma_f32_16x16x32_bf16((a), (b), (c), 0, 0, 0)

__device__ __forceinline__ unsigned short f2bf(float v) {
    unsigned u = __float_as_uint(v);
    return (unsigned short)((u + 0x7fffu + ((u >> 16) & 1u)) >> 16);  // RN
}
__device__ __forceinline__ float bf2f(unsigned short h) {
    return __uint_as_float(((unsigned)h) << 16);
}

// B=8, C=256, H=W=64, N=4096, HID=128
#define NB 8
#define NC 256
#define NN 4096
#define HID 128
#define ELEMS (NB * NN * HID)            // 4,194,304 per [B,N,128] bf16 buffer

// ---------------- kernel 1: projections (unchanged from round 1) ----------------
__global__ __launch_bounds__(256, 3)
void proj_kernel(const float* __restrict__ x,
                 const float* __restrict__ w_theta,
                 const float* __restrict__ w_phi,
                 const float* __restrict__ w_g,
                 unsigned short* __restrict__ Qhi, unsigned short* __restrict__ Qlo,
                 unsigned short* __restrict__ Khi, unsigned short* __restrict__ Klo,
                 unsigned short* __restrict__ Vt) {
    __shared__ float Wl[16][128];        // [c][o]
    __shared__ float Xl[16][132];        // [c][n] +4 pad
    __shared__ unsigned int Tbuf[128][65]; // [o][n_local] packed (hi<<16)|lo

    const int t = threadIdx.x;
    const int n0 = blockIdx.x * 128;
    const int which = blockIdx.y;
    const int b = blockIdx.z;
    const float* wsel = (which == 0) ? w_theta : ((which == 1) ? w_phi : w_g);
    const int ty = t >> 4, tx = t & 15;

    float acc[8][8];
#pragma unroll
    for (int i = 0; i < 8; i++)
#pragma unroll
        for (int j = 0; j < 8; j++) acc[i][j] = 0.f;

    const int wo = t >> 1;           // 0..127
    const int wj = (t & 1) * 8;      // 0 or 8
    const int xc = t >> 4;           // 0..15
    const int xn = (t & 15) * 8;

    for (int k0 = 0; k0 < NC; k0 += 16) {
        __syncthreads();
        {   // stage W tile (transpose to [c][o])
            const float* src = wsel + wo * NC + k0 + wj;
            float4 a = *(const float4*)src;
            float4 b4 = *(const float4*)(src + 4);
            Wl[wj + 0][wo] = a.x;  Wl[wj + 1][wo] = a.y;
            Wl[wj + 2][wo] = a.z;  Wl[wj + 3][wo] = a.w;
            Wl[wj + 4][wo] = b4.x; Wl[wj + 5][wo] = b4.y;
            Wl[wj + 6][wo] = b4.z; Wl[wj + 7][wo] = b4.w;
        }
        {   // stage X tile
            const float* src = x + ((size_t)(b * NC + k0 + xc)) * NN + n0 + xn;
            float4 a = *(const float4*)src;
            float4 b4 = *(const float4*)(src + 4);
            *(float4*)&Xl[xc][xn] = a;
            *(float4*)&Xl[xc][xn + 4] = b4;
        }
        __syncthreads();
#pragma unroll
        for (int cc = 0; cc < 16; cc++) {
            float a0[8], b0[8];
            *(float4*)&a0[0] = *(const float4*)&Wl[cc][ty * 8];
            *(float4*)&a0[4] = *(const float4*)&Wl[cc][ty * 8 + 4];
            *(float4*)&b0[0] = *(const float4*)&Xl[cc][tx * 8];
            *(float4*)&b0[4] = *(const float4*)&Xl[cc][tx * 8 + 4];
#pragma unroll
            for (int i = 0; i < 8; i++)
#pragma unroll
                for (int j = 0; j < 8; j++) acc[i][j] = fmaf(a0[i], b0[j], acc[i][j]);
        }
    }

    if (which == 2) {
#pragma unroll
        for (int i = 0; i < 8; i++) {
            int o = ty * 8 + i;
            u16x8 v;
#pragma unroll
            for (int j = 0; j < 8; j++) v[j] = f2bf(acc[i][j]);
            *(u16x8*)(Vt + ((size_t)(b * HID + o)) * NN + n0 + tx * 8) = v;
        }
    } else {
        unsigned short* dh = (which == 0) ? Qhi : Khi;
        unsigned short* dl = (which == 0) ? Qlo : Klo;
        for (int h = 0; h < 2; h++) {
            __syncthreads();
            if ((tx >> 3) == h) {
                int txl = tx & 7;
#pragma unroll
                for (int i = 0; i < 8; i++)
#pragma unroll
                    for (int j = 0; j < 8; j++) {
                        float v = acc[i][j];
                        unsigned short hi = f2bf(v);
                        unsigned short lo = f2bf(v - bf2f(hi));
                        Tbuf[ty * 8 + i][txl * 8 + j] = (((unsigned)hi) << 16) | lo;
                    }
            }
            __syncthreads();
            {
                int nl = t & 63;
                int og = (t >> 6) * 32;
                int n = n0 + h * 64 + nl;
                u16x8 vh[4], vl[4];
#pragma unroll
                for (int k = 0; k < 32; k++) {
                    unsigned u = Tbuf[og + k][nl];
                    vh[k >> 3][k & 7] = (unsigned short)(u >> 16);
                    vl[k >> 3][k & 7] = (unsigned short)(u & 0xffffu);
                }
                size_t base = ((size_t)(b * NN + n)) * HID + og;
#pragma unroll
                for (int q = 0; q < 4; q++) {
                    *(u16x8*)(dh + base + q * 8) = vh[q];
                    *(u16x8*)(dl + base + q * 8) = vl[q];
                }
            }
        }
    }
}

// ---------------- kernel 2: flash attention v2 (P_lds layout FIXED) ----------------
// KVBLK=64; row-sum via ones-MFMA; defer-max (headroom 65 in exp2-domain).
// P stored as flat 64-wide padded row: P_lds[wave][16 rows][72] (144B rows, 16B-aligned).
// PV/row-sum consume it as TWO k=32 MFMAs (kk = 0, 32) — identical pattern to round 1.
// MODE 0: normalize in-kernel, write Y[B,N,128]. MODE 1: write partial
// Yp[z][B,N,128] (unnormalized bf16) + Ms/Ss[z][B,N] f32.
template<int MODE>
__global__ __launch_bounds__(256, 4)
void attn_kernel(const unsigned short* __restrict__ Qhi, const unsigned short* __restrict__ Qlo,
                 const unsigned short* __restrict__ Khi, const unsigned short* __restrict__ Klo,
                 const unsigned short* __restrict__ Vt,
                 unsigned short* __restrict__ Yp, float* __restrict__ Ms, float* __restrict__ Ss,
                 int kv_len) {
    __shared__ __align__(16) unsigned short P_lds[4][16][72];  // [wave][q-row][64 cols + 8 pad]

    const int t = threadIdx.x;
    const int w = t >> 6, lane = t & 63;
    const int g = lane >> 4, c = lane & 15;
    const int b = blockIdx.y, z = blockIdx.z;
    const int q0 = blockIdx.x * 64 + w * 16;
    const float CEXP = 16.32223142f;  // sqrt(128) * log2(e)

    bf16x8 ones;
#pragma unroll
    for (int j = 0; j < 8; j++) ones[j] = (short)0x3F80;

    bf16x8 qhi[4], qlo[4];
    {
        const size_t qoff = ((size_t)(b * NN) + q0 + c) * HID + g * 8;
#pragma unroll
        for (int ks = 0; ks < 4; ks++) {
            qhi[ks] = *(const bf16x8*)(Qhi + qoff + ks * 32);
            qlo[ks] = *(const bf16x8*)(Qlo + qoff + ks * 32);
        }
    }

    float mstar[4] = {-3.0e38f, -3.0e38f, -3.0e38f, -3.0e38f};  // exp2-domain
    f32x4 yacc[8];
    f32x4 sacc = (f32x4){0.f, 0.f, 0.f, 0.f};
#pragma unroll
    for (int dt = 0; dt < 8; dt++) yacc[dt] = (f32x4){0.f, 0.f, 0.f, 0.f};

    const int kvb = z * kv_len;
    const unsigned short* kbh = Khi + ((size_t)(b * NN) + kvb) * HID;
    const unsigned short* kbl = Klo + ((size_t)(b * NN) + kvb) * HID;
    const unsigned short* vb = Vt + ((size_t)(b * HID)) * NN + kvb;

    for (int kv0 = 0; kv0 < kv_len; kv0 += 64) {
        f32x4 stv[4];
        __builtin_amdgcn_s_setprio(1);
#pragma unroll
        for (int tt = 0; tt < 4; tt++) {
            f32x4 shh = (f32x4){0.f, 0.f, 0.f, 0.f};
            f32x4 shl = shh, slh = shh;
            const size_t ko = (size_t)(kv0 + tt * 16 + c) * HID + g * 8;
#pragma unroll
            for (int ks = 0; ks < 4; ks++) {
                bf16x8 kh = *(const bf16x8*)(kbh + ko + ks * 32);
                bf16x8 kl = *(const bf16x8*)(kbl + ko + ks * 32);
                shh = MFMA16(qhi[ks], kh, shh);   // 3-term hi/lo: ~f32-accurate logits
                shl = MFMA16(qhi[ks], kl, shl);
                slh = MFMA16(qlo[ks], kh, slh);
            }
            f32x4 s = shh + shl + slh;
            stv[tt] = s * CEXP;                   // exp2-domain
        }
        __builtin_amdgcn_s_setprio(0);

        // per-row max over the 64-col tile (rows 4g+r live in the 16 c-lanes)
        float rmax[4];
#pragma unroll
        for (int r = 0; r < 4; r++)
            rmax[r] = fmaxf(fmaxf(stv[0][r], stv[1][r]), fmaxf(stv[2][r], stv[3][r]));
#pragma unroll
        for (int s = 1; s <= 8; s <<= 1)
#pragma unroll
            for (int r = 0; r < 4; r++) rmax[r] = fmaxf(rmax[r], __shfl_xor(rmax[r], s, 64));

        // defer-max: only rescale when a row exceeds headroom (p stays <= 2^65)
        bool need = (rmax[0] > mstar[0] + 65.f) || (rmax[1] > mstar[1] + 65.f) ||
                    (rmax[2] > mstar[2] + 65.f) || (rmax[3] > mstar[3] + 65.f);
        if (__any(need)) {
#pragma unroll
            for (int r = 0; r < 4; r++) {
                float nm = fmaxf(mstar[r], rmax[r]);
                float corr = exp2f(mstar[r] - nm);   // first tile: ~exp2(-huge)=0
                mstar[r] = nm;
                sacc[r] *= corr;
#pragma unroll
                for (int dt = 0; dt < 8; dt++) yacc[dt][r] *= corr;
            }
        }

        // P -> LDS in C/D layout (row 4g+r, col tt*16+c)
#pragma unroll
        for (int tt = 0; tt < 4; tt++)
#pragma unroll
            for (int r = 0; r < 4; r++)
                P_lds[w][g * 4 + r][tt * 16 + c] = f2bf(exp2f(stv[tt][r] - mstar[r]));

        asm volatile("s_waitcnt lgkmcnt(0)" ::: "memory");  // same-wave LDS RAW
        __builtin_amdgcn_sched_barrier(0);

        __builtin_amdgcn_s_setprio(1);
#pragma unroll
        for (int kk = 0; kk < 2; kk++) {
            bf16x8 pf = *(const bf16x8*)&P_lds[w][c][kk * 32 + g * 8];  // A-frag: row c, k=g*8..+7
            sacc = MFMA16(pf, ones, sacc);        // row-sum for free (same bf16 P as PV)
#pragma unroll
            for (int dt = 0; dt < 8; dt++) {
                bf16x8 vf = *(const bf16x8*)(vb + (size_t)(dt * 16 + c) * NN + kv0 + kk * 32 + g * 8);
                yacc[dt] = MFMA16(pf, vf, yacc[dt]);
            }
        }
        __builtin_amdgcn_s_setprio(0);
    }

    if (MODE == 0) {
        float inv[4];
#pragma unroll
        for (int r = 0; r < 4; r++) inv[r] = 1.0f / sacc[r];
#pragma unroll
        for (int dt = 0; dt < 8; dt++)
#pragma unroll
            for (int r = 0; r < 4; r++)
                Yp[((size_t)(b * NN) + q0 + g * 4 + r) * HID + dt * 16 + c] = f2bf(yacc[dt][r] * inv[r]);
    } else {
        const size_t base = (((size_t)z * NB + b) * NN + q0);
#pragma unroll
        for (int dt = 0; dt < 8; dt++)
#pragma unroll
            for (int r = 0; r < 4; r++)
                Yp[(base + g * 4 + r) * HID + dt * 16 + c] = f2bf(yacc[dt][r]);
        if (c == 0) {
#pragma unroll
            for (int r = 0; r < 4; r++) {
                Ms[base + g * 4 + r] = mstar[r];
                Ss[base + g * 4 + r] = sacc[r];
            }
        }
    }
}

// ---------------- kernel 3: (combine +) output projection + residual ----------------
// NS==0: Yp is normalized Y. NS==2: combine two partials using Ms/Ss.
template<int NS>
__global__ __launch_bounds__(256, 3)
void out_kernel(const float* __restrict__ x, const float* __restrict__ w_out,
                const unsigned short* __restrict__ Yp,
                const float* __restrict__ Ms, const float* __restrict__ Ss,
                float* __restrict__ out) {
    __shared__ unsigned short Yl[64][130];  // +2 pad: conflict-free column reads

    const int t = threadIdx.x;
    const int b = blockIdx.y;
    const int n0 = blockIdx.x * 64;
    {
        int n = t & 63, og = (t >> 6) * 32;
        size_t qi = (size_t)b * NN + n0 + n;
        if (NS == 0) {
            const unsigned short* src = Yp + qi * HID + og;
#pragma unroll
            for (int q = 0; q < 4; q++) {
                u16x8 v = *(const u16x8*)(src + q * 8);
#pragma unroll
                for (int j = 0; j < 4; j++) {
                    unsigned u = (unsigned)v[2 * j] | (((unsigned)v[2 * j + 1]) << 16);
                    *(unsigned*)&Yl[n][og + q * 8 + 2 * j] = u;
                }
            }
        } else {
            const size_t NBNN = (size_t)NB * NN;
            float m0 = Ms[qi], m1 = Ms[NBNN + qi];
            float M = fmaxf(m0, m1);
            float w0 = exp2f(m0 - M), w1 = exp2f(m1 - M);
            float S = Ss[qi] * w0 + Ss[NBNN + qi] * w1;
            float invS = 1.f / S;
            w0 *= invS; w1 *= invS;
            const unsigned short* s0 = Yp + qi * HID + og;
            const unsigned short* s1 = Yp + (NBNN + qi) * HID + og;
#pragma unroll
            for (int q = 0; q < 4; q++) {
                u16x8 a = *(const u16x8*)(s0 + q * 8);
                u16x8 b8 = *(const u16x8*)(s1 + q * 8);
#pragma unroll
                for (int j = 0; j < 4; j++) {
                    float f0 = bf2f(a[2 * j]) * w0 + bf2f(b8[2 * j]) * w1;
                    float f1 = bf2f(a[2 * j + 1]) * w0 + bf2f(b8[2 * j + 1]) * w1;
                    unsigned u = (unsigned)f2bf(f0) | (((unsigned)f2bf(f1)) << 16);
                    *(unsigned*)&Yl[n][og + q * 8 + 2 * j] = u;
                }
            }
        }
    }
    __syncthreads();

    const int c0 = (__builtin_amdgcn_readfirstlane(t) >> 6) << 6;  // wave-uniform -> scalar w loads
    const int n = t & 63;
    float acc[64];
#pragma unroll
    for (int i = 0; i < 64; i++) acc[i] = 0.f;

    for (int og = 0; og < HID; og += 8) {
        float yv[8];
#pragma unroll
        for (int j = 0; j < 4; j++) {
            unsigned u = *(const unsigned*)&Yl[n][og + 2 * j];
            yv[2 * j] = bf2f((unsigned short)(u & 0xffffu));
            yv[2 * j + 1] = bf2f((unsigned short)(u >> 16));
        }
        const float* wr = w_out + (size_t)c0 * HID + og;
#pragma unroll
        for (int i = 0; i < 64; i++) {
            const float* wi = wr + i * HID;
            float a = acc[i];
            a = fmaf(wi[0], yv[0], a); a = fmaf(wi[1], yv[1], a);
            a = fmaf(wi[2], yv[2], a); a = fmaf(wi[3], yv[3], a);
            a = fmaf(wi[4], yv[4], a); a = fmaf(wi[5], yv[5], a);
            a = fmaf(wi[6], yv[6], a); a = fmaf(wi[7], yv[7], a);
            acc[i] = a;
        }
    }
#pragma unroll
    for (int i = 0; i < 64; i++) {
        size_t idx = ((size_t)(b * NC + c0 + i)) * NN + n0 + n;
        out[idx] = x[idx] + acc[i];
    }
}

// ---------------- launch ----------------
extern "C" void kernel_launch(void* const* d_in, const int* in_sizes, int n_in,
                              void* d_out, int out_size, void* d_ws, size_t ws_size,
                              hipStream_t stream) {
    const float* x = (const float*)d_in[0];
    const float* w_phi = (const float*)d_in[1];
    const float* w_theta = (const float*)d_in[2];
    const float* w_g = (const float*)d_in[3];
    const float* w_out = (const float*)d_in[4];
    float* out = (float*)d_out;

    const size_t BUF = (size_t)ELEMS * 2;      // 8,388,608 B per bf16 buffer
    const size_t MSB = (size_t)NB * NN * 4;    // 131,072 B per [B,N] f32 array
    if (ws_size < 6 * BUF) return;             // proven >= 6*BUF in round 1

    unsigned short* Qhi = (unsigned short*)d_ws;
    unsigned short* Qlo = (unsigned short*)((char*)d_ws + 1 * BUF);
    unsigned short* Khi = (unsigned short*)((char*)d_ws + 2 * BUF);
    unsigned short* Klo = (unsigned short*)((char*)d_ws + 3 * BUF);
    unsigned short* Vt  = (unsigned short*)((char*)d_ws + 4 * BUF);

    proj_kernel<<<dim3(32, 3, 8), 256, 0, stream>>>(x, w_theta, w_phi, w_g,
                                                    Qhi, Qlo, Khi, Klo, Vt);

    if (ws_size >= 7 * BUF + 4 * MSB) {
        // split-kv x2: 1024 blocks -> 4 waves/SIMD
        unsigned short* Yp = (unsigned short*)((char*)d_ws + 5 * BUF);
        float* Ms = (float*)((char*)d_ws + 7 * BUF);
        float* Ss = (float*)((char*)d_ws + 7 * BUF + 2 * MSB);
        attn_kernel<1><<<dim3(64, NB, 2), 256, 0, stream>>>(Qhi, Qlo, Khi, Klo, Vt,
                                                            Yp, Ms, Ss, NN / 2);
        out_kernel<2><<<dim3(64, NB), 256, 0, stream>>>(x, w_out, Yp, Ms, Ss, out);
    } else {
        unsigned short* Yb = (unsigned short*)((char*)d_ws + 5 * BUF);
        attn_kernel<0><<<dim3(64, NB, 1), 256, 0, stream>>>(Qhi, Qlo, Khi, Klo, Vt,
                                                            Yb, nullptr, nullptr, NN);
        out_kernel<0><<<dim3(64, NB), 256, 0, stream>>>(x, w_out, Yb, nullptr, nullptr, out);
    }
}

// Round 4
// 492.620 us; speedup vs baseline: 1.8665x; 1.8665x over previous
//
#include <hip/hip_runtime.h>

// ---------------- types / helpers ----------------
typedef __attribute__((ext_vector_type(8))) short bf16x8;   // 8 bf16 in 4 VGPRs (MFMA A/B frag)
typedef __attribute__((ext_vector_type(4))) float f32x4;    // MFMA C/D frag
typedef __attribute__((ext_vector_type(8))) unsigned short u16x8;

#define MFMA16(a, b, c) __builtin_amdgcn_mfma_f32_16x16x32_bf16((a), (b), (c), 0, 0, 0)

__device__ __forceinline__ unsigned short f2bf(float v) {
    unsigned u = __float_as_uint(v);
    return (unsigned short)((u + 0x7fffu + ((u >> 16) & 1u)) >> 16);  // RN
}
__device__ __forceinline__ float bf2f(unsigned short h) {
    return __uint_as_float(((unsigned)h) << 16);
}
// async global->LDS DMA, 16B/lane; LDS dest = base + lane*16 (hardware), global src per-lane.
__device__ __forceinline__ void gll16(const void* g, void* l) {
    __builtin_amdgcn_global_load_lds(
        (const __attribute__((address_space(1))) unsigned int*)g,
        (__attribute__((address_space(3))) unsigned int*)l, 16, 0, 0);
}

// B=8, C=256, H=W=64, N=4096, HID=128
#define NB 8
#define NC 256
#define NN 4096
#define HID 128
#define ELEMS (NB * NN * HID)            // 4,194,304 per [B,N,128] bf16 buffer

// ---------------- kernel 1: projections (unchanged) ----------------
__global__ __launch_bounds__(256, 3)
void proj_kernel(const float* __restrict__ x,
                 const float* __restrict__ w_theta,
                 const float* __restrict__ w_phi,
                 const float* __restrict__ w_g,
                 unsigned short* __restrict__ Qhi, unsigned short* __restrict__ Qlo,
                 unsigned short* __restrict__ Khi, unsigned short* __restrict__ Klo,
                 unsigned short* __restrict__ Vt) {
    __shared__ float Wl[16][128];
    __shared__ float Xl[16][132];
    __shared__ unsigned int Tbuf[128][65];

    const int t = threadIdx.x;
    const int n0 = blockIdx.x * 128;
    const int which = blockIdx.y;
    const int b = blockIdx.z;
    const float* wsel = (which == 0) ? w_theta : ((which == 1) ? w_phi : w_g);
    const int ty = t >> 4, tx = t & 15;

    float acc[8][8];
#pragma unroll
    for (int i = 0; i < 8; i++)
#pragma unroll
        for (int j = 0; j < 8; j++) acc[i][j] = 0.f;

    const int wo = t >> 1;
    const int wj = (t & 1) * 8;
    const int xc = t >> 4;
    const int xn = (t & 15) * 8;

    for (int k0 = 0; k0 < NC; k0 += 16) {
        __syncthreads();
        {
            const float* src = wsel + wo * NC + k0 + wj;
            float4 a = *(const float4*)src;
            float4 b4 = *(const float4*)(src + 4);
            Wl[wj + 0][wo] = a.x;  Wl[wj + 1][wo] = a.y;
            Wl[wj + 2][wo] = a.z;  Wl[wj + 3][wo] = a.w;
            Wl[wj + 4][wo] = b4.x; Wl[wj + 5][wo] = b4.y;
            Wl[wj + 6][wo] = b4.z; Wl[wj + 7][wo] = b4.w;
        }
        {
            const float* src = x + ((size_t)(b * NC + k0 + xc)) * NN + n0 + xn;
            float4 a = *(const float4*)src;
            float4 b4 = *(const float4*)(src + 4);
            *(float4*)&Xl[xc][xn] = a;
            *(float4*)&Xl[xc][xn + 4] = b4;
        }
        __syncthreads();
#pragma unroll
        for (int cc = 0; cc < 16; cc++) {
            float a0[8], b0[8];
            *(float4*)&a0[0] = *(const float4*)&Wl[cc][ty * 8];
            *(float4*)&a0[4] = *(const float4*)&Wl[cc][ty * 8 + 4];
            *(float4*)&b0[0] = *(const float4*)&Xl[cc][tx * 8];
            *(float4*)&b0[4] = *(const float4*)&Xl[cc][tx * 8 + 4];
#pragma unroll
            for (int i = 0; i < 8; i++)
#pragma unroll
                for (int j = 0; j < 8; j++) acc[i][j] = fmaf(a0[i], b0[j], acc[i][j]);
        }
    }

    if (which == 2) {
#pragma unroll
        for (int i = 0; i < 8; i++) {
            int o = ty * 8 + i;
            u16x8 v;
#pragma unroll
            for (int j = 0; j < 8; j++) v[j] = f2bf(acc[i][j]);
            *(u16x8*)(Vt + ((size_t)(b * HID + o)) * NN + n0 + tx * 8) = v;
        }
    } else {
        unsigned short* dh = (which == 0) ? Qhi : Khi;
        unsigned short* dl = (which == 0) ? Qlo : Klo;
        for (int h = 0; h < 2; h++) {
            __syncthreads();
            if ((tx >> 3) == h) {
                int txl = tx & 7;
#pragma unroll
                for (int i = 0; i < 8; i++)
#pragma unroll
                    for (int j = 0; j < 8; j++) {
                        float v = acc[i][j];
                        unsigned short hi = f2bf(v);
                        unsigned short lo = f2bf(v - bf2f(hi));
                        Tbuf[ty * 8 + i][txl * 8 + j] = (((unsigned)hi) << 16) | lo;
                    }
            }
            __syncthreads();
            {
                int nl = t & 63;
                int og = (t >> 6) * 32;
                int n = n0 + h * 64 + nl;
                u16x8 vh[4], vl[4];
#pragma unroll
                for (int k = 0; k < 32; k++) {
                    unsigned u = Tbuf[og + k][nl];
                    vh[k >> 3][k & 7] = (unsigned short)(u >> 16);
                    vl[k >> 3][k & 7] = (unsigned short)(u & 0xffffu);
                }
                size_t base = ((size_t)(b * NN + n)) * HID + og;
#pragma unroll
                for (int q = 0; q < 4; q++) {
                    *(u16x8*)(dh + base + q * 8) = vh[q];
                    *(u16x8*)(dl + base + q * 8) = vl[q];
                }
            }
        }
    }
}

// ---------------- kernel 2: flash attention v3 — LDS-staged async pipeline ----------------
// KVBLK=32. Per iter the block stages Khi(8K)+Klo(8K)+V(8K) via global_load_lds into a
// double buffer (24 stage-instrs split 6/wave), counted vmcnt + raw s_barrier (T3-min).
// K swizzle: chunk' = q ^ (row&7); V swizzle: chunk' = m ^ ((d>>1)&3) — both applied on
// the GLOBAL source (linear LDS dest) and on the ds_read address; 2-way = free.
// XCD pinning: b = blockIdx.x & 7.
template<int MODE>   // 0: single-split, normalize+write Y; 1: split-kv x2, write partials
__global__ __launch_bounds__(256, 2)
void attn_kernel(const unsigned short* __restrict__ Qhi, const unsigned short* __restrict__ Qlo,
                 const unsigned short* __restrict__ Khi, const unsigned short* __restrict__ Klo,
                 const unsigned short* __restrict__ Vt,
                 unsigned short* __restrict__ Yp, float* __restrict__ Ms, float* __restrict__ Ss,
                 int kv_len) {
    __shared__ __align__(16) unsigned char KV_lds[2][24576];   // Khi[0,8K) Klo[8K,16K) V[16K,24K)
    __shared__ __align__(16) unsigned short P_lds[4][16][40];  // per-wave P, rows 80B

    const int t = threadIdx.x;
    const int w = t >> 6, lane = t & 63;
    const int g = lane >> 4, c = lane & 15;
    const int bid = blockIdx.x;
    const int b = bid & 7;                       // batch -> XCD pin
    const int z = (MODE == 1) ? ((bid >> 3) & 1) : 0;
    const int qx = (MODE == 1) ? (bid >> 4) : (bid >> 3);
    const int q0 = qx * 64 + w * 16;
    const float CEXP = 16.32223142f;             // sqrt(128) * log2(e)

    bf16x8 ones;
#pragma unroll
    for (int j = 0; j < 8; j++) ones[j] = (short)0x3F80;

    const int kvb = z * kv_len;
    const char* KhG = (const char*)(Khi + ((size_t)(b * NN) + kvb) * HID);
    const char* KlG = (const char*)(Klo + ((size_t)(b * NN) + kvb) * HID);
    const char* VG  = (const char*)(Vt + ((size_t)(b * HID)) * NN + kvb);

    // ---- stage lane constants ----
    const int kr_lo = (lane >> 4);          // K: row-within-4 per instr
    const int kq    = lane & 15;            // K: lds chunk = lane&15
    const int vr_lo = (lane >> 2);          // V: row-within-16 per instr
    const int vm    = lane & 3;             // V: lds chunk

    // ---- prologue: stage tile 0 into buf 0 ----
    {
        const size_t kv0b = 0;
#pragma unroll
        for (int s = 0; s < 2; ++s) {
            int i = w * 2 + s;                       // instr 0..7
            int r = i * 4 + kr_lo;                   // K row 0..31
            int qg = kq ^ (r & 7);
            gll16(KhG + (kv0b + r) * 256 + qg * 16, &KV_lds[0][i * 1024]);
            gll16(KlG + (kv0b + r) * 256 + qg * 16, &KV_lds[0][8192 + i * 1024]);
            int d = i * 16 + vr_lo;                  // V row 0..127
            int mg = vm ^ ((d >> 1) & 3);
            gll16(VG + (size_t)d * 8192 + kv0b * 2 + mg * 16, &KV_lds[0][16384 + i * 1024]);
        }
    }

    // ---- Q fragments ----
    bf16x8 qhi[4], qlo[4];
    {
        const size_t qoff = ((size_t)(b * NN) + q0 + c) * HID + g * 8;
#pragma unroll
        for (int ks = 0; ks < 4; ks++) {
            qhi[ks] = *(const bf16x8*)(Qhi + qoff + ks * 32);
            qlo[ks] = *(const bf16x8*)(Qlo + qoff + ks * 32);
        }
    }

    float mstar[4] = {-3.0e38f, -3.0e38f, -3.0e38f, -3.0e38f};
    f32x4 yacc[8];
    f32x4 sacc = (f32x4){0.f, 0.f, 0.f, 0.f};
#pragma unroll
    for (int dt = 0; dt < 8; dt++) yacc[dt] = (f32x4){0.f, 0.f, 0.f, 0.f};

    const int nt = kv_len >> 5;   // KVBLK=32
    int cur = 0;

    for (int tI = 0; tI < nt; ++tI) {
        // ---- stage tile tI+1 into the other buffer (async, 6 instrs/wave) ----
        if (tI + 1 < nt) {
            const size_t kvn = (size_t)(tI + 1) * 32;
            unsigned char* nb = &KV_lds[cur ^ 1][0];
#pragma unroll
            for (int s = 0; s < 2; ++s) {
                int i = w * 2 + s;
                int r = i * 4 + kr_lo;
                int qg = kq ^ (r & 7);
                gll16(KhG + (kvn + r) * 256 + qg * 16, nb + i * 1024);
                gll16(KlG + (kvn + r) * 256 + qg * 16, nb + 8192 + i * 1024);
                int d = i * 16 + vr_lo;
                int mg = vm ^ ((d >> 1) & 3);
                gll16(VG + (size_t)d * 8192 + kvn * 2 + mg * 16, nb + 16384 + i * 1024);
            }
            asm volatile("s_waitcnt vmcnt(6)" ::: "memory");   // tile tI landed, tI+1 in flight
        } else {
            asm volatile("s_waitcnt vmcnt(0)" ::: "memory");   // last tile: drain
        }
        __builtin_amdgcn_sched_barrier(0);
        __builtin_amdgcn_s_barrier();                          // all waves' stage of tile tI done

        const unsigned char* Kh_l = &KV_lds[cur][0];
        const unsigned char* Kl_l = &KV_lds[cur][8192];
        const unsigned char* V_l  = &KV_lds[cur][16384];

        // ---- QK^T (3-term hi/lo) from LDS ----
        f32x4 stv[2];
        __builtin_amdgcn_s_setprio(1);
#pragma unroll
        for (int tt = 0; tt < 2; tt++) {
            f32x4 shh = (f32x4){0.f, 0.f, 0.f, 0.f};
            f32x4 shl = shh, slh = shh;
            const int rloc = tt * 16 + c;
            const int kbase = rloc * 256;
            const int key = c & 7;
#pragma unroll
            for (int ks = 0; ks < 4; ks++) {
                const int off = kbase + (((ks * 4 + g) ^ key) * 16);
                bf16x8 kh = *(const bf16x8*)(Kh_l + off);
                bf16x8 kl = *(const bf16x8*)(Kl_l + off);
                shh = MFMA16(qhi[ks], kh, shh);
                shl = MFMA16(qhi[ks], kl, shl);
                slh = MFMA16(qlo[ks], kh, slh);
            }
            f32x4 s = shh + shl + slh;
            stv[tt] = s * CEXP;                    // exp2-domain
        }
        __builtin_amdgcn_s_setprio(0);

        // ---- online softmax over 32 cols ----
        float rmax[4];
#pragma unroll
        for (int r = 0; r < 4; r++) rmax[r] = fmaxf(stv[0][r], stv[1][r]);
#pragma unroll
        for (int s = 1; s <= 8; s <<= 1)
#pragma unroll
            for (int r = 0; r < 4; r++) rmax[r] = fmaxf(rmax[r], __shfl_xor(rmax[r], s, 64));

        bool need = (rmax[0] > mstar[0] + 65.f) || (rmax[1] > mstar[1] + 65.f) ||
                    (rmax[2] > mstar[2] + 65.f) || (rmax[3] > mstar[3] + 65.f);
        if (__any(need)) {
#pragma unroll
            for (int r = 0; r < 4; r++) {
                float nm = fmaxf(mstar[r], rmax[r]);
                float corr = exp2f(mstar[r] - nm);
                mstar[r] = nm;
                sacc[r] *= corr;
#pragma unroll
                for (int dt = 0; dt < 8; dt++) yacc[dt][r] *= corr;
            }
        }

#pragma unroll
        for (int r = 0; r < 4; r++) {
            P_lds[w][g * 4 + r][c]      = f2bf(exp2f(stv[0][r] - mstar[r]));
            P_lds[w][g * 4 + r][16 + c] = f2bf(exp2f(stv[1][r] - mstar[r]));
        }
        asm volatile("s_waitcnt lgkmcnt(0)" ::: "memory");
        __builtin_amdgcn_sched_barrier(0);

        // ---- PV + ones-sum from LDS ----
        __builtin_amdgcn_s_setprio(1);
        {
            bf16x8 pf = *(const bf16x8*)&P_lds[w][c][g * 8];
            sacc = MFMA16(pf, ones, sacc);
            const int vkey = (c >> 1) & 3;
#pragma unroll
            for (int dt = 0; dt < 8; dt++) {
                bf16x8 vf = *(const bf16x8*)(V_l + (dt * 16 + c) * 64 + ((g ^ vkey) * 16));
                yacc[dt] = MFMA16(pf, vf, yacc[dt]);
            }
        }
        __builtin_amdgcn_s_setprio(0);

        __builtin_amdgcn_sched_barrier(0);
        __builtin_amdgcn_s_barrier();              // reads of buf[cur] done; safe to overwrite next iter
        cur ^= 1;
    }

    if (MODE == 0) {
        float inv[4];
#pragma unroll
        for (int r = 0; r < 4; r++) inv[r] = 1.0f / sacc[r];
#pragma unroll
        for (int dt = 0; dt < 8; dt++)
#pragma unroll
            for (int r = 0; r < 4; r++)
                Yp[((size_t)(b * NN) + q0 + g * 4 + r) * HID + dt * 16 + c] = f2bf(yacc[dt][r] * inv[r]);
    } else {
        const size_t base = (((size_t)z * NB + b) * NN + q0);
#pragma unroll
        for (int dt = 0; dt < 8; dt++)
#pragma unroll
            for (int r = 0; r < 4; r++)
                Yp[(base + g * 4 + r) * HID + dt * 16 + c] = f2bf(yacc[dt][r]);
        if (c == 0) {
#pragma unroll
            for (int r = 0; r < 4; r++) {
                Ms[base + g * 4 + r] = mstar[r];
                Ss[base + g * 4 + r] = sacc[r];
            }
        }
    }
}

// ---------------- kernel 3: (combine +) output projection + residual ----------------
template<int NS>
__global__ __launch_bounds__(256, 3)
void out_kernel(const float* __restrict__ x, const float* __restrict__ w_out,
                const unsigned short* __restrict__ Yp,
                const float* __restrict__ Ms, const float* __restrict__ Ss,
                float* __restrict__ out) {
    __shared__ unsigned short Yl[64][130];

    const int t = threadIdx.x;
    const int b = blockIdx.y;
    const int n0 = blockIdx.x * 64;
    {
        int n = t & 63, og = (t >> 6) * 32;
        size_t qi = (size_t)b * NN + n0 + n;
        if (NS == 0) {
            const unsigned short* src = Yp + qi * HID + og;
#pragma unroll
            for (int q = 0; q < 4; q++) {
                u16x8 v = *(const u16x8*)(src + q * 8);
#pragma unroll
                for (int j = 0; j < 4; j++) {
                    unsigned u = (unsigned)v[2 * j] | (((unsigned)v[2 * j + 1]) << 16);
                    *(unsigned*)&Yl[n][og + q * 8 + 2 * j] = u;
                }
            }
        } else {
            const size_t NBNN = (size_t)NB * NN;
            float m0 = Ms[qi], m1 = Ms[NBNN + qi];
            float M = fmaxf(m0, m1);
            float w0 = exp2f(m0 - M), w1 = exp2f(m1 - M);
            float S = Ss[qi] * w0 + Ss[NBNN + qi] * w1;
            float invS = 1.f / S;
            w0 *= invS; w1 *= invS;
            const unsigned short* s0 = Yp + qi * HID + og;
            const unsigned short* s1 = Yp + (NBNN + qi) * HID + og;
#pragma unroll
            for (int q = 0; q < 4; q++) {
                u16x8 a = *(const u16x8*)(s0 + q * 8);
                u16x8 b8 = *(const u16x8*)(s1 + q * 8);
#pragma unroll
                for (int j = 0; j < 4; j++) {
                    float f0 = bf2f(a[2 * j]) * w0 + bf2f(b8[2 * j]) * w1;
                    float f1 = bf2f(a[2 * j + 1]) * w0 + bf2f(b8[2 * j + 1]) * w1;
                    unsigned u = (unsigned)f2bf(f0) | (((unsigned)f2bf(f1)) << 16);
                    *(unsigned*)&Yl[n][og + q * 8 + 2 * j] = u;
                }
            }
        }
    }
    __syncthreads();

    const int c0 = (__builtin_amdgcn_readfirstlane(t) >> 6) << 6;
    const int n = t & 63;
    float acc[64];
#pragma unroll
    for (int i = 0; i < 64; i++) acc[i] = 0.f;

    for (int og = 0; og < HID; og += 8) {
        float yv[8];
#pragma unroll
        for (int j = 0; j < 4; j++) {
            unsigned u = *(const unsigned*)&Yl[n][og + 2 * j];
            yv[2 * j] = bf2f((unsigned short)(u & 0xffffu));
            yv[2 * j + 1] = bf2f((unsigned short)(u >> 16));
        }
        const float* wr = w_out + (size_t)c0 * HID + og;
#pragma unroll
        for (int i = 0; i < 64; i++) {
            const float* wi = wr + i * HID;
            float a = acc[i];
            a = fmaf(wi[0], yv[0], a); a = fmaf(wi[1], yv[1], a);
            a = fmaf(wi[2], yv[2], a); a = fmaf(wi[3], yv[3], a);
            a = fmaf(wi[4], yv[4], a); a = fmaf(wi[5], yv[5], a);
            a = fmaf(wi[6], yv[6], a); a = fmaf(wi[7], yv[7], a);
            acc[i] = a;
        }
    }
#pragma unroll
    for (int i = 0; i < 64; i++) {
        size_t idx = ((size_t)(b * NC + c0 + i)) * NN + n0 + n;
        out[idx] = x[idx] + acc[i];
    }
}

// ---------------- launch ----------------
extern "C" void kernel_launch(void* const* d_in, const int* in_sizes, int n_in,
                              void* d_out, int out_size, void* d_ws, size_t ws_size,
                              hipStream_t stream) {
    const float* x = (const float*)d_in[0];
    const float* w_phi = (const float*)d_in[1];
    const float* w_theta = (const float*)d_in[2];
    const float* w_g = (const float*)d_in[3];
    const float* w_out = (const float*)d_in[4];
    float* out = (float*)d_out;

    const size_t BUF = (size_t)ELEMS * 2;      // 8,388,608 B per bf16 buffer
    const size_t MSB = (size_t)NB * NN * 4;    // 131,072 B per [B,N] f32 array
    if (ws_size < 6 * BUF) return;

    unsigned short* Qhi = (unsigned short*)d_ws;
    unsigned short* Qlo = (unsigned short*)((char*)d_ws + 1 * BUF);
    unsigned short* Khi = (unsigned short*)((char*)d_ws + 2 * BUF);
    unsigned short* Klo = (unsigned short*)((char*)d_ws + 3 * BUF);
    unsigned short* Vt  = (unsigned short*)((char*)d_ws + 4 * BUF);

    proj_kernel<<<dim3(32, 3, 8), 256, 0, stream>>>(x, w_theta, w_phi, w_g,
                                                    Qhi, Qlo, Khi, Klo, Vt);

    if (ws_size >= 7 * BUF + 4 * MSB) {
        // split-kv x2: 1024 blocks, flat grid, b = bid&7 pins batch -> XCD
        unsigned short* Yp = (unsigned short*)((char*)d_ws + 5 * BUF);
        float* Ms = (float*)((char*)d_ws + 7 * BUF);
        float* Ss = (float*)((char*)d_ws + 7 * BUF + 2 * MSB);
        attn_kernel<1><<<dim3(1024), 256, 0, stream>>>(Qhi, Qlo, Khi, Klo, Vt,
                                                       Yp, Ms, Ss, NN / 2);
        out_kernel<2><<<dim3(64, NB), 256, 0, stream>>>(x, w_out, Yp, Ms, Ss, out);
    } else {
        unsigned short* Yb = (unsigned short*)((char*)d_ws + 5 * BUF);
        attn_kernel<0><<<dim3(512), 256, 0, stream>>>(Qhi, Qlo, Khi, Klo, Vt,
                                                      Yb, nullptr, nullptr, NN);
        out_kernel<0><<<dim3(64, NB), 256, 0, stream>>>(x, w_out, Yb, nullptr, nullptr, out);
    }
}

// Round 5
// 317.333 us; speedup vs baseline: 2.8975x; 1.5524x over previous
//
#include <hip/hip_runtime.h>

// ---------------- types / helpers ----------------
typedef __attribute__((ext_vector_type(8))) short bf16x8;   // 8 bf16 in 4 VGPRs (MFMA A/B frag)
typedef __attribute__((ext_vector_type(4))) float f32x4;    // MFMA C/D frag
typedef __attribute__((ext_vector_type(8))) unsigned short u16x8;

#define MFMA16(a, b, c) __builtin_amdgcn_mfma_f32_16x16x32_bf16((a), (b), (c), 0, 0, 0)

__device__ __forceinline__ unsigned short f2bf(float v) {
    unsigned u = __float_as_uint(v);
    return (unsigned short)((u + 0x7fffu + ((u >> 16) & 1u)) >> 16);  // RN
}
__device__ __forceinline__ float bf2f(unsigned short h) {
    return __uint_as_float(((unsigned)h) << 16);
}
// async global->LDS DMA, 16B/lane; LDS dest = base + lane*16 (hardware), global src per-lane.
__device__ __forceinline__ void gll16(const void* g, void* l) {
    __builtin_amdgcn_global_load_lds(
        (const __attribute__((address_space(1))) unsigned int*)g,
        (__attribute__((address_space(3))) unsigned int*)l, 16, 0, 0);
}

// B=8, C=256, H=W=64, N=4096, HID=128
#define NB 8
#define NC 256
#define NN 4096
#define HID 128
#define ELEMS (NB * NN * HID)            // 4,194,304 per [B,N,128] bf16 buffer

// ---------------- kernel 1: projections v2 — hi/lo bf16 MFMA ----------------
// Per block (which, b, 128-wide n-tile): O[128 o][128 n] = W[128x256] x X[256 x 128n].
// A = W rows (read from global f32, split hi/lo in-reg), B = x chunk staged in LDS
// [64 c][129 n] f32 (pad-1 row -> 2-way-free strided column reads), split hi/lo in-reg.
// which<2 (theta/phi): 3-term hi/lo MFMA, Tbuf transpose epilogue -> Q/K [n][128] hi/lo.
// which==2 (g): 1-term, direct store Vt[o][n].
__global__ __launch_bounds__(256, 2)
void proj_kernel(const float* __restrict__ x,
                 const float* __restrict__ w_theta,
                 const float* __restrict__ w_phi,
                 const float* __restrict__ w_g,
                 unsigned short* __restrict__ Qhi, unsigned short* __restrict__ Qlo,
                 unsigned short* __restrict__ Khi, unsigned short* __restrict__ Klo,
                 unsigned short* __restrict__ Vt) {
    __shared__ __align__(16) unsigned char LdsRaw[128 * 65 * 4];  // 33,280 B (union)
    float (*xs)[129] = reinterpret_cast<float(*)[129]>(LdsRaw);   // [64][129] f32
    unsigned int (*Tb)[65] = reinterpret_cast<unsigned int(*)[65]>(LdsRaw);  // [128][65]

    const int t = threadIdx.x;
    const int w = t >> 6, lane = t & 63;
    const int g = lane >> 4, c = lane & 15;
    const int n0 = blockIdx.x * 128;
    const int which = blockIdx.y;
    const int b = blockIdx.z;
    const float* wsel = (which == 0) ? w_theta : ((which == 1) ? w_phi : w_g);

    f32x4 acc[2][8];
#pragma unroll
    for (int mi = 0; mi < 2; mi++)
#pragma unroll
        for (int nt = 0; nt < 8; nt++) acc[mi][nt] = (f32x4){0.f, 0.f, 0.f, 0.f};

    // stage map: row = w*16 + (l>>2) (k-dim), cols nq..nq+31 (coalesced global)
    const int srow = w * 16 + (lane >> 2);
    const int snq = (lane & 3) * 32;

    for (int k0 = 0; k0 < NC; k0 += 64) {
        __syncthreads();
        {   // stage x chunk [64 c][128 n] -> padded LDS
            const float* src = x + ((size_t)(b * NC + k0 + srow)) * NN + n0 + snq;
            float4 v[8];
#pragma unroll
            for (int u = 0; u < 8; u++) v[u] = *(const float4*)(src + 4 * u);
#pragma unroll
            for (int u = 0; u < 8; u++) {
                xs[srow][snq + 4 * u + 0] = v[u].x;
                xs[srow][snq + 4 * u + 1] = v[u].y;
                xs[srow][snq + 4 * u + 2] = v[u].z;
                xs[srow][snq + 4 * u + 3] = v[u].w;
            }
        }
        __syncthreads();

#pragma unroll
        for (int s = 0; s < 2; s++) {
            // A-frags: W rows from global f32 (L2-hot), split hi/lo
            bf16x8 wh[2], wl[2];
#pragma unroll
            for (int mi = 0; mi < 2; mi++) {
                const float* wp = wsel + (size_t)(w * 32 + mi * 16 + c) * NC + k0 + s * 32 + g * 8;
                float av[8];
                *(float4*)&av[0] = *(const float4*)wp;
                *(float4*)&av[4] = *(const float4*)(wp + 4);
#pragma unroll
                for (int j = 0; j < 8; j++) {
                    unsigned short hh = f2bf(av[j]);
                    wh[mi][j] = (short)hh;
                    if (which < 2) wl[mi][j] = (short)f2bf(av[j] - bf2f(hh));
                }
            }
#pragma unroll
            for (int nt = 0; nt < 8; nt++) {
                float bv[8];
#pragma unroll
                for (int j = 0; j < 8; j++) bv[j] = xs[s * 32 + g * 8 + j][nt * 16 + c];
                bf16x8 xh, xl;
#pragma unroll
                for (int j = 0; j < 8; j++) {
                    unsigned short hh = f2bf(bv[j]);
                    xh[j] = (short)hh;
                    if (which < 2) xl[j] = (short)f2bf(bv[j] - bf2f(hh));
                }
#pragma unroll
                for (int mi = 0; mi < 2; mi++) {
                    acc[mi][nt] = MFMA16(wh[mi], xh, acc[mi][nt]);
                    if (which < 2) {
                        acc[mi][nt] = MFMA16(wh[mi], xl, acc[mi][nt]);  // hi*lo
                        acc[mi][nt] = MFMA16(wl[mi], xh, acc[mi][nt]);  // lo*hi
                    }
                }
            }
        }
    }

    if (which == 2) {
        // D[row=o, col=n] -> Vt[b][o][n] direct (1-term bf16)
#pragma unroll
        for (int mi = 0; mi < 2; mi++)
#pragma unroll
            for (int nt = 0; nt < 8; nt++)
#pragma unroll
                for (int r = 0; r < 4; r++) {
                    int o = w * 32 + mi * 16 + 4 * g + r;
                    Vt[((size_t)(b * HID + o)) * NN + n0 + nt * 16 + c] = f2bf(acc[mi][nt][r]);
                }
    } else {
        // transpose epilogue (round-1-proven Tbuf pattern): -> Q/K [n][128] hi/lo
        unsigned short* dh = (which == 0) ? Qhi : Khi;
        unsigned short* dl = (which == 0) ? Qlo : Klo;
        for (int h = 0; h < 2; h++) {
            __syncthreads();   // also protects xs->Tb union reuse on h==0
#pragma unroll
            for (int mi = 0; mi < 2; mi++)
#pragma unroll
                for (int q2 = 0; q2 < 4; q2++) {
                    int nt = h * 4 + q2;
#pragma unroll
                    for (int r = 0; r < 4; r++) {
                        float v = acc[mi][nt][r];
                        unsigned short hi = f2bf(v);
                        unsigned short lo = f2bf(v - bf2f(hi));
                        Tb[w * 32 + mi * 16 + 4 * g + r][q2 * 16 + c] = (((unsigned)hi) << 16) | lo;
                    }
                }
            __syncthreads();
            {
                int nl = t & 63;
                int og = (t >> 6) * 32;
                int n = n0 + h * 64 + nl;
                u16x8 vh[4], vl[4];
#pragma unroll
                for (int k = 0; k < 32; k++) {
                    unsigned u = Tb[og + k][nl];
                    vh[k >> 3][k & 7] = (unsigned short)(u >> 16);
                    vl[k >> 3][k & 7] = (unsigned short)(u & 0xffffu);
                }
                size_t base = ((size_t)(b * NN + n)) * HID + og;
#pragma unroll
                for (int q = 0; q < 4; q++) {
                    *(u16x8*)(dh + base + q * 8) = vh[q];
                    *(u16x8*)(dl + base + q * 8) = vl[q];
                }
            }
        }
    }
}

// ---------------- kernel 2: flash attention (UNCHANGED from round 4) ----------------
template<int MODE>   // 0: single-split, normalize+write Y; 1: split-kv x2, write partials
__global__ __launch_bounds__(256, 2)
void attn_kernel(const unsigned short* __restrict__ Qhi, const unsigned short* __restrict__ Qlo,
                 const unsigned short* __restrict__ Khi, const unsigned short* __restrict__ Klo,
                 const unsigned short* __restrict__ Vt,
                 unsigned short* __restrict__ Yp, float* __restrict__ Ms, float* __restrict__ Ss,
                 int kv_len) {
    __shared__ __align__(16) unsigned char KV_lds[2][24576];   // Khi[0,8K) Klo[8K,16K) V[16K,24K)
    __shared__ __align__(16) unsigned short P_lds[4][16][40];  // per-wave P, rows 80B

    const int t = threadIdx.x;
    const int w = t >> 6, lane = t & 63;
    const int g = lane >> 4, c = lane & 15;
    const int bid = blockIdx.x;
    const int b = bid & 7;                       // batch -> XCD pin
    const int z = (MODE == 1) ? ((bid >> 3) & 1) : 0;
    const int qx = (MODE == 1) ? (bid >> 4) : (bid >> 3);
    const int q0 = qx * 64 + w * 16;
    const float CEXP = 16.32223142f;             // sqrt(128) * log2(e)

    bf16x8 ones;
#pragma unroll
    for (int j = 0; j < 8; j++) ones[j] = (short)0x3F80;

    const int kvb = z * kv_len;
    const char* KhG = (const char*)(Khi + ((size_t)(b * NN) + kvb) * HID);
    const char* KlG = (const char*)(Klo + ((size_t)(b * NN) + kvb) * HID);
    const char* VG  = (const char*)(Vt + ((size_t)(b * HID)) * NN + kvb);

    const int kr_lo = (lane >> 4);
    const int kq    = lane & 15;
    const int vr_lo = (lane >> 2);
    const int vm    = lane & 3;

    {   // prologue: stage tile 0 into buf 0
        const size_t kv0b = 0;
#pragma unroll
        for (int s = 0; s < 2; ++s) {
            int i = w * 2 + s;
            int r = i * 4 + kr_lo;
            int qg = kq ^ (r & 7);
            gll16(KhG + (kv0b + r) * 256 + qg * 16, &KV_lds[0][i * 1024]);
            gll16(KlG + (kv0b + r) * 256 + qg * 16, &KV_lds[0][8192 + i * 1024]);
            int d = i * 16 + vr_lo;
            int mg = vm ^ ((d >> 1) & 3);
            gll16(VG + (size_t)d * 8192 + kv0b * 2 + mg * 16, &KV_lds[0][16384 + i * 1024]);
        }
    }

    bf16x8 qhi[4], qlo[4];
    {
        const size_t qoff = ((size_t)(b * NN) + q0 + c) * HID + g * 8;
#pragma unroll
        for (int ks = 0; ks < 4; ks++) {
            qhi[ks] = *(const bf16x8*)(Qhi + qoff + ks * 32);
            qlo[ks] = *(const bf16x8*)(Qlo + qoff + ks * 32);
        }
    }

    float mstar[4] = {-3.0e38f, -3.0e38f, -3.0e38f, -3.0e38f};
    f32x4 yacc[8];
    f32x4 sacc = (f32x4){0.f, 0.f, 0.f, 0.f};
#pragma unroll
    for (int dt = 0; dt < 8; dt++) yacc[dt] = (f32x4){0.f, 0.f, 0.f, 0.f};

    const int nt = kv_len >> 5;   // KVBLK=32
    int cur = 0;

    for (int tI = 0; tI < nt; ++tI) {
        if (tI + 1 < nt) {
            const size_t kvn = (size_t)(tI + 1) * 32;
            unsigned char* nb = &KV_lds[cur ^ 1][0];
#pragma unroll
            for (int s = 0; s < 2; ++s) {
                int i = w * 2 + s;
                int r = i * 4 + kr_lo;
                int qg = kq ^ (r & 7);
                gll16(KhG + (kvn + r) * 256 + qg * 16, nb + i * 1024);
                gll16(KlG + (kvn + r) * 256 + qg * 16, nb + 8192 + i * 1024);
                int d = i * 16 + vr_lo;
                int mg = vm ^ ((d >> 1) & 3);
                gll16(VG + (size_t)d * 8192 + kvn * 2 + mg * 16, nb + 16384 + i * 1024);
            }
            asm volatile("s_waitcnt vmcnt(6)" ::: "memory");
        } else {
            asm volatile("s_waitcnt vmcnt(0)" ::: "memory");
        }
        __builtin_amdgcn_sched_barrier(0);
        __builtin_amdgcn_s_barrier();

        const unsigned char* Kh_l = &KV_lds[cur][0];
        const unsigned char* Kl_l = &KV_lds[cur][8192];
        const unsigned char* V_l  = &KV_lds[cur][16384];

        f32x4 stv[2];
        __builtin_amdgcn_s_setprio(1);
#pragma unroll
        for (int tt = 0; tt < 2; tt++) {
            f32x4 shh = (f32x4){0.f, 0.f, 0.f, 0.f};
            f32x4 shl = shh, slh = shh;
            const int rloc = tt * 16 + c;
            const int kbase = rloc * 256;
            const int key = c & 7;
#pragma unroll
            for (int ks = 0; ks < 4; ks++) {
                const int off = kbase + (((ks * 4 + g) ^ key) * 16);
                bf16x8 kh = *(const bf16x8*)(Kh_l + off);
                bf16x8 kl = *(const bf16x8*)(Kl_l + off);
                shh = MFMA16(qhi[ks], kh, shh);
                shl = MFMA16(qhi[ks], kl, shl);
                slh = MFMA16(qlo[ks], kh, slh);
            }
            f32x4 s = shh + shl + slh;
            stv[tt] = s * CEXP;
        }
        __builtin_amdgcn_s_setprio(0);

        float rmax[4];
#pragma unroll
        for (int r = 0; r < 4; r++) rmax[r] = fmaxf(stv[0][r], stv[1][r]);
#pragma unroll
        for (int s = 1; s <= 8; s <<= 1)
#pragma unroll
            for (int r = 0; r < 4; r++) rmax[r] = fmaxf(rmax[r], __shfl_xor(rmax[r], s, 64));

        bool need = (rmax[0] > mstar[0] + 65.f) || (rmax[1] > mstar[1] + 65.f) ||
                    (rmax[2] > mstar[2] + 65.f) || (rmax[3] > mstar[3] + 65.f);
        if (__any(need)) {
#pragma unroll
            for (int r = 0; r < 4; r++) {
                float nm = fmaxf(mstar[r], rmax[r]);
                float corr = exp2f(mstar[r] - nm);
                mstar[r] = nm;
                sacc[r] *= corr;
#pragma unroll
                for (int dt = 0; dt < 8; dt++) yacc[dt][r] *= corr;
            }
        }

#pragma unroll
        for (int r = 0; r < 4; r++) {
            P_lds[w][g * 4 + r][c]      = f2bf(exp2f(stv[0][r] - mstar[r]));
            P_lds[w][g * 4 + r][16 + c] = f2bf(exp2f(stv[1][r] - mstar[r]));
        }
        asm volatile("s_waitcnt lgkmcnt(0)" ::: "memory");
        __builtin_amdgcn_sched_barrier(0);

        __builtin_amdgcn_s_setprio(1);
        {
            bf16x8 pf = *(const bf16x8*)&P_lds[w][c][g * 8];
            sacc = MFMA16(pf, ones, sacc);
            const int vkey = (c >> 1) & 3;
#pragma unroll
            for (int dt = 0; dt < 8; dt++) {
                bf16x8 vf = *(const bf16x8*)(V_l + (dt * 16 + c) * 64 + ((g ^ vkey) * 16));
                yacc[dt] = MFMA16(pf, vf, yacc[dt]);
            }
        }
        __builtin_amdgcn_s_setprio(0);

        __builtin_amdgcn_sched_barrier(0);
        __builtin_amdgcn_s_barrier();
        cur ^= 1;
    }

    if (MODE == 0) {
        float inv[4];
#pragma unroll
        for (int r = 0; r < 4; r++) inv[r] = 1.0f / sacc[r];
#pragma unroll
        for (int dt = 0; dt < 8; dt++)
#pragma unroll
            for (int r = 0; r < 4; r++)
                Yp[((size_t)(b * NN) + q0 + g * 4 + r) * HID + dt * 16 + c] = f2bf(yacc[dt][r] * inv[r]);
    } else {
        const size_t base = (((size_t)z * NB + b) * NN + q0);
#pragma unroll
        for (int dt = 0; dt < 8; dt++)
#pragma unroll
            for (int r = 0; r < 4; r++)
                Yp[(base + g * 4 + r) * HID + dt * 16 + c] = f2bf(yacc[dt][r]);
        if (c == 0) {
#pragma unroll
            for (int r = 0; r < 4; r++) {
                Ms[base + g * 4 + r] = mstar[r];
                Ss[base + g * 4 + r] = sacc[r];
            }
        }
    }
}

// ---------------- kernel 3: output projection v2 — bf16 MFMA + residual ----------------
// out[c][n] = x[c][n] + sum_o w_out[c][o] * Y[n][o].  A = w_out (global f32 -> bf16 hi),
// B = Y staged in LDS [128 n][136 o] (16B-aligned rows, conflict-free b128 reads).
// NS==2 folds the split-kv combine into staging.
template<int NS>
__global__ __launch_bounds__(256, 2)
void out_kernel(const float* __restrict__ x, const float* __restrict__ w_out,
                const unsigned short* __restrict__ Yp,
                const float* __restrict__ Ms, const float* __restrict__ Ss,
                float* __restrict__ out) {
    __shared__ __align__(16) unsigned short Yl[128][136];  // 34,816 B

    const int t = threadIdx.x;
    const int w = t >> 6, lane = t & 63;
    const int g = lane >> 4, c = lane & 15;
    const int n0 = blockIdx.x * 128;
    const int b = blockIdx.y;

    {   // stage (+combine) Y tile
        int nl = t >> 1, oh = (t & 1) * 64;
        size_t qi = (size_t)b * NN + n0 + nl;
        if (NS == 0) {
            const unsigned short* src = Yp + qi * HID + oh;
#pragma unroll
            for (int i = 0; i < 8; i++)
                *(u16x8*)&Yl[nl][oh + i * 8] = *(const u16x8*)(src + i * 8);
        } else {
            const size_t NBNN = (size_t)NB * NN;
            float m0 = Ms[qi], m1 = Ms[NBNN + qi];
            float M = fmaxf(m0, m1);
            float w0 = exp2f(m0 - M), w1 = exp2f(m1 - M);
            float S = Ss[qi] * w0 + Ss[NBNN + qi] * w1;
            float invS = 1.f / S;
            w0 *= invS; w1 *= invS;
            const unsigned short* s0 = Yp + qi * HID + oh;
            const unsigned short* s1 = Yp + (NBNN + qi) * HID + oh;
#pragma unroll
            for (int i = 0; i < 8; i++) {
                u16x8 a = *(const u16x8*)(s0 + i * 8);
                u16x8 b8 = *(const u16x8*)(s1 + i * 8);
                u16x8 vv;
#pragma unroll
                for (int j = 0; j < 8; j++)
                    vv[j] = f2bf(bf2f(a[j]) * w0 + bf2f(b8[j]) * w1);
                *(u16x8*)&Yl[nl][oh + i * 8] = vv;
            }
        }
    }
    __syncthreads();

    f32x4 acc[4][8];
#pragma unroll
    for (int mi = 0; mi < 4; mi++)
#pragma unroll
        for (int nt = 0; nt < 8; nt++) acc[mi][nt] = (f32x4){0.f, 0.f, 0.f, 0.f};

#pragma unroll
    for (int s = 0; s < 4; s++) {
        bf16x8 wf[4];
#pragma unroll
        for (int mi = 0; mi < 4; mi++) {
            const float* wp = w_out + (size_t)(w * 64 + mi * 16 + c) * HID + s * 32 + g * 8;
            float av[8];
            *(float4*)&av[0] = *(const float4*)wp;
            *(float4*)&av[4] = *(const float4*)(wp + 4);
#pragma unroll
            for (int j = 0; j < 8; j++) wf[mi][j] = (short)f2bf(av[j]);
        }
#pragma unroll
        for (int nt = 0; nt < 8; nt++) {
            bf16x8 yf = *(const bf16x8*)&Yl[nt * 16 + c][s * 32 + g * 8];
#pragma unroll
            for (int mi = 0; mi < 4; mi++) acc[mi][nt] = MFMA16(wf[mi], yf, acc[mi][nt]);
        }
    }

    // epilogue: D[row=c_glob, col=n] + residual
#pragma unroll
    for (int mi = 0; mi < 4; mi++)
#pragma unroll
        for (int nt = 0; nt < 8; nt++)
#pragma unroll
            for (int r = 0; r < 4; r++) {
                int cg = w * 64 + mi * 16 + 4 * g + r;
                size_t idx = ((size_t)(b * NC + cg)) * NN + n0 + nt * 16 + c;
                out[idx] = x[idx] + acc[mi][nt][r];
            }
}

// ---------------- launch ----------------
extern "C" void kernel_launch(void* const* d_in, const int* in_sizes, int n_in,
                              void* d_out, int out_size, void* d_ws, size_t ws_size,
                              hipStream_t stream) {
    const float* x = (const float*)d_in[0];
    const float* w_phi = (const float*)d_in[1];
    const float* w_theta = (const float*)d_in[2];
    const float* w_g = (const float*)d_in[3];
    const float* w_out = (const float*)d_in[4];
    float* out = (float*)d_out;

    const size_t BUF = (size_t)ELEMS * 2;      // 8,388,608 B per bf16 buffer
    const size_t MSB = (size_t)NB * NN * 4;    // 131,072 B per [B,N] f32 array
    if (ws_size < 6 * BUF) return;

    unsigned short* Qhi = (unsigned short*)d_ws;
    unsigned short* Qlo = (unsigned short*)((char*)d_ws + 1 * BUF);
    unsigned short* Khi = (unsigned short*)((char*)d_ws + 2 * BUF);
    unsigned short* Klo = (unsigned short*)((char*)d_ws + 3 * BUF);
    unsigned short* Vt  = (unsigned short*)((char*)d_ws + 4 * BUF);

    proj_kernel<<<dim3(32, 3, 8), 256, 0, stream>>>(x, w_theta, w_phi, w_g,
                                                    Qhi, Qlo, Khi, Klo, Vt);

    if (ws_size >= 7 * BUF + 4 * MSB) {
        // split-kv x2: 1024 blocks, flat grid, b = bid&7 pins batch -> XCD
        unsigned short* Yp = (unsigned short*)((char*)d_ws + 5 * BUF);
        float* Ms = (float*)((char*)d_ws + 7 * BUF);
        float* Ss = (float*)((char*)d_ws + 7 * BUF + 2 * MSB);
        attn_kernel<1><<<dim3(1024), 256, 0, stream>>>(Qhi, Qlo, Khi, Klo, Vt,
                                                       Yp, Ms, Ss, NN / 2);
        out_kernel<2><<<dim3(32, NB), 256, 0, stream>>>(x, w_out, Yp, Ms, Ss, out);
    } else {
        unsigned short* Yb = (unsigned short*)((char*)d_ws + 5 * BUF);
        attn_kernel<0><<<dim3(512), 256, 0, stream>>>(Qhi, Qlo, Khi, Klo, Vt,
                                                      Yb, nullptr, nullptr, NN);
        out_kernel<0><<<dim3(32, NB), 256, 0, stream>>>(x, w_out, Yb, nullptr, nullptr, out);
    }
}

// Round 6
// 233.352 us; speedup vs baseline: 3.9403x; 1.3599x over previous
//
#include <hip/hip_runtime.h>

// ---------------- types / helpers ----------------
typedef __attribute__((ext_vector_type(8))) short bf16x8;   // 8 bf16 in 4 VGPRs (MFMA A/B frag)
typedef __attribute__((ext_vector_type(4))) float f32x4;    // MFMA C/D frag
typedef __attribute__((ext_vector_type(8))) unsigned short u16x8;

#define MFMA16(a, b, c) __builtin_amdgcn_mfma_f32_16x16x32_bf16((a), (b), (c), 0, 0, 0)

__device__ __forceinline__ unsigned short f2bf(float v) {
    unsigned u = __float_as_uint(v);
    return (unsigned short)((u + 0x7fffu + ((u >> 16) & 1u)) >> 16);  // RN
}
__device__ __forceinline__ float bf2f(unsigned short h) {
    return __uint_as_float(((unsigned)h) << 16);
}
// async global->LDS DMA, 16B/lane; LDS dest = base + lane*16 (hardware), global src per-lane.
__device__ __forceinline__ void gll16(const void* g, void* l) {
    __builtin_amdgcn_global_load_lds(
        (const __attribute__((address_space(1))) unsigned int*)g,
        (__attribute__((address_space(3))) unsigned int*)l, 16, 0, 0);
}
// max with row_ror:<N> DPP (16-lane row rotate) — VALU-only cross-lane reduce step
template<int CTRL>
__device__ __forceinline__ float dppmax(float x) {
    int v = __builtin_amdgcn_update_dpp(0, __float_as_int(x), CTRL, 0xf, 0xf, true);
    return fmaxf(x, __int_as_float(v));
}
__device__ __forceinline__ float rowmax16(float x) {
    x = dppmax<0x121>(x);   // ror:1
    x = dppmax<0x122>(x);   // ror:2
    x = dppmax<0x124>(x);   // ror:4
    x = dppmax<0x128>(x);   // ror:8
    return x;
}

// B=8, C=256, H=W=64, N=4096, HID=128
#define NB 8
#define NC 256
#define NN 4096
#define HID 128
#define ELEMS (NB * NN * HID)            // 4,194,304 per [B,N,128] bf16 buffer

// ---------------- kernel 1: projections — hi/lo bf16 MFMA ----------------
// which==0 (theta): output pre-scaled by sqrt(128)*log2(e) so attn logits land in
// exp2-domain with no per-iter scaling. which==1 (phi): plain hi/lo. which==2 (g): bf16.
__global__ __launch_bounds__(256, 2)
void proj_kernel(const float* __restrict__ x,
                 const float* __restrict__ w_theta,
                 const float* __restrict__ w_phi,
                 const float* __restrict__ w_g,
                 unsigned short* __restrict__ Qhi, unsigned short* __restrict__ Qlo,
                 unsigned short* __restrict__ Khi, unsigned short* __restrict__ Klo,
                 unsigned short* __restrict__ Vt) {
    __shared__ __align__(16) unsigned char LdsRaw[128 * 65 * 4];  // 33,280 B (union)
    float (*xs)[129] = reinterpret_cast<float(*)[129]>(LdsRaw);   // [64][129] f32
    unsigned int (*Tb)[65] = reinterpret_cast<unsigned int(*)[65]>(LdsRaw);  // [128][65]

    const int t = threadIdx.x;
    const int w = t >> 6, lane = t & 63;
    const int g = lane >> 4, c = lane & 15;
    const int n0 = blockIdx.x * 128;
    const int which = blockIdx.y;
    const int b = blockIdx.z;
    const float* wsel = (which == 0) ? w_theta : ((which == 1) ? w_phi : w_g);

    f32x4 acc[2][8];
#pragma unroll
    for (int mi = 0; mi < 2; mi++)
#pragma unroll
        for (int nt = 0; nt < 8; nt++) acc[mi][nt] = (f32x4){0.f, 0.f, 0.f, 0.f};

    const int srow = w * 16 + (lane >> 2);
    const int snq = (lane & 3) * 32;

    for (int k0 = 0; k0 < NC; k0 += 64) {
        __syncthreads();
        {   // stage x chunk [64 c][128 n] -> padded LDS
            const float* src = x + ((size_t)(b * NC + k0 + srow)) * NN + n0 + snq;
            float4 v[8];
#pragma unroll
            for (int u = 0; u < 8; u++) v[u] = *(const float4*)(src + 4 * u);
#pragma unroll
            for (int u = 0; u < 8; u++) {
                xs[srow][snq + 4 * u + 0] = v[u].x;
                xs[srow][snq + 4 * u + 1] = v[u].y;
                xs[srow][snq + 4 * u + 2] = v[u].z;
                xs[srow][snq + 4 * u + 3] = v[u].w;
            }
        }
        __syncthreads();

#pragma unroll
        for (int s = 0; s < 2; s++) {
            bf16x8 wh[2], wl[2];
#pragma unroll
            for (int mi = 0; mi < 2; mi++) {
                const float* wp = wsel + (size_t)(w * 32 + mi * 16 + c) * NC + k0 + s * 32 + g * 8;
                float av[8];
                *(float4*)&av[0] = *(const float4*)wp;
                *(float4*)&av[4] = *(const float4*)(wp + 4);
#pragma unroll
                for (int j = 0; j < 8; j++) {
                    unsigned short hh = f2bf(av[j]);
                    wh[mi][j] = (short)hh;
                    if (which < 2) wl[mi][j] = (short)f2bf(av[j] - bf2f(hh));
                }
            }
#pragma unroll
            for (int nt = 0; nt < 8; nt++) {
                float bv[8];
#pragma unroll
                for (int j = 0; j < 8; j++) bv[j] = xs[s * 32 + g * 8 + j][nt * 16 + c];
                bf16x8 xh, xl;
#pragma unroll
                for (int j = 0; j < 8; j++) {
                    unsigned short hh = f2bf(bv[j]);
                    xh[j] = (short)hh;
                    if (which < 2) xl[j] = (short)f2bf(bv[j] - bf2f(hh));
                }
#pragma unroll
                for (int mi = 0; mi < 2; mi++) {
                    acc[mi][nt] = MFMA16(wh[mi], xh, acc[mi][nt]);
                    if (which < 2) {
                        acc[mi][nt] = MFMA16(wh[mi], xl, acc[mi][nt]);  // hi*lo
                        acc[mi][nt] = MFMA16(wl[mi], xh, acc[mi][nt]);  // lo*hi
                    }
                }
            }
        }
    }

    if (which == 2) {
#pragma unroll
        for (int mi = 0; mi < 2; mi++)
#pragma unroll
            for (int nt = 0; nt < 8; nt++)
#pragma unroll
                for (int r = 0; r < 4; r++) {
                    int o = w * 32 + mi * 16 + 4 * g + r;
                    Vt[((size_t)(b * HID + o)) * NN + n0 + nt * 16 + c] = f2bf(acc[mi][nt][r]);
                }
    } else {
        unsigned short* dh = (which == 0) ? Qhi : Khi;
        unsigned short* dl = (which == 0) ? Qlo : Klo;
        const float qscale = (which == 0) ? 16.32223142f : 1.0f;  // sqrt(128)*log2(e) folded into theta
        for (int h = 0; h < 2; h++) {
            __syncthreads();   // protects xs->Tb union reuse
#pragma unroll
            for (int mi = 0; mi < 2; mi++)
#pragma unroll
                for (int q2 = 0; q2 < 4; q2++) {
                    int nt = h * 4 + q2;
#pragma unroll
                    for (int r = 0; r < 4; r++) {
                        float v = acc[mi][nt][r] * qscale;
                        unsigned short hi = f2bf(v);
                        unsigned short lo = f2bf(v - bf2f(hi));
                        Tb[w * 32 + mi * 16 + 4 * g + r][q2 * 16 + c] = (((unsigned)hi) << 16) | lo;
                    }
                }
            __syncthreads();
            {
                int nl = t & 63;
                int og = (t >> 6) * 32;
                int n = n0 + h * 64 + nl;
                u16x8 vh[4], vl[4];
#pragma unroll
                for (int k = 0; k < 32; k++) {
                    unsigned u = Tb[og + k][nl];
                    vh[k >> 3][k & 7] = (unsigned short)(u >> 16);
                    vl[k >> 3][k & 7] = (unsigned short)(u & 0xffffu);
                }
                size_t base = ((size_t)(b * NN + n)) * HID + og;
#pragma unroll
                for (int q = 0; q < 4; q++) {
                    *(u16x8*)(dh + base + q * 8) = vh[q];
                    *(u16x8*)(dl + base + q * 8) = vl[q];
                }
            }
        }
    }
}

// ---------------- kernel 2: flash attention v4 — 8-wave shared staging + DPP softmax ----------------
// 512 threads; waves w=0..7 each own a 16-row q-strip (block covers 128 q-rows) and share
// the staged K/V double buffer. Per iter each wave issues 3 gll16 (1 Khi, 1 Klo, 1 V);
// steady-state s_waitcnt vmcnt(3). Row-max via VALU DPP row_ror reduce (no LDS pipe).
// Q pre-scaled: logits arrive in exp2-domain.
template<int MODE>   // 0: single-split, normalize+write Y; 1: split-kv x2, write partials
__global__ __launch_bounds__(512, 2)
void attn_kernel(const unsigned short* __restrict__ Qhi, const unsigned short* __restrict__ Qlo,
                 const unsigned short* __restrict__ Khi, const unsigned short* __restrict__ Klo,
                 const unsigned short* __restrict__ Vt,
                 unsigned short* __restrict__ Yp, float* __restrict__ Ms, float* __restrict__ Ss,
                 int kv_len) {
    __shared__ __align__(16) unsigned char KV_lds[2][24576];   // Khi[0,8K) Klo[8K,16K) V[16K,24K)
    __shared__ __align__(16) unsigned short P_lds[8][16][40];  // per-wave P, rows 80B

    const int t = threadIdx.x;
    const int w = t >> 6, lane = t & 63;
    const int g = lane >> 4, c = lane & 15;
    const int bid = blockIdx.x;
    const int b = bid & 7;                       // batch -> XCD pin
    const int z = (MODE == 1) ? ((bid >> 3) & 1) : 0;
    const int qx = (MODE == 1) ? (bid >> 4) : (bid >> 3);
    const int q0 = qx * 128 + w * 16;

    bf16x8 ones;
#pragma unroll
    for (int j = 0; j < 8; j++) ones[j] = (short)0x3F80;

    const int kvb = z * kv_len;
    const char* KhG = (const char*)(Khi + ((size_t)(b * NN) + kvb) * HID);
    const char* KlG = (const char*)(Klo + ((size_t)(b * NN) + kvb) * HID);
    const char* VG  = (const char*)(Vt + ((size_t)(b * HID)) * NN + kvb);

    // stage lane constants: instr index i == w (one Khi + one Klo + one V per wave)
    const int krow = w * 4 + (lane >> 4);        // K row 0..31
    const int kq   = lane & 15;                  // K 16B-chunk slot
    const int kqg  = kq ^ (krow & 7);            // swizzled global chunk
    const int vrow = w * 16 + (lane >> 2);       // V row 0..127
    const int vm   = lane & 3;                   // V 16B-chunk slot
    const int vmg  = vm ^ ((vrow >> 1) & 3);     // swizzled global chunk

    {   // prologue: stage tile 0 into buf 0 (3 loads/wave)
        gll16(KhG + (size_t)krow * 256 + kqg * 16, &KV_lds[0][w * 1024]);
        gll16(KlG + (size_t)krow * 256 + kqg * 16, &KV_lds[0][8192 + w * 1024]);
        gll16(VG + (size_t)vrow * 8192 + vmg * 16, &KV_lds[0][16384 + w * 1024]);
    }

    bf16x8 qhi[4], qlo[4];
    {
        const size_t qoff = ((size_t)(b * NN) + q0 + c) * HID + g * 8;
#pragma unroll
        for (int ks = 0; ks < 4; ks++) {
            qhi[ks] = *(const bf16x8*)(Qhi + qoff + ks * 32);
            qlo[ks] = *(const bf16x8*)(Qlo + qoff + ks * 32);
        }
    }

    float mstar[4] = {-3.0e38f, -3.0e38f, -3.0e38f, -3.0e38f};
    f32x4 yacc[8];
    f32x4 sacc = (f32x4){0.f, 0.f, 0.f, 0.f};
#pragma unroll
    for (int dt = 0; dt < 8; dt++) yacc[dt] = (f32x4){0.f, 0.f, 0.f, 0.f};

    const int nt = kv_len >> 5;   // KVBLK=32
    int cur = 0;

    for (int tI = 0; tI < nt; ++tI) {
        if (tI + 1 < nt) {
            const size_t kvn = (size_t)(tI + 1) * 32;
            unsigned char* nb = &KV_lds[cur ^ 1][0];
            gll16(KhG + (kvn + krow) * 256 + kqg * 16, nb + w * 1024);
            gll16(KlG + (kvn + krow) * 256 + kqg * 16, nb + 8192 + w * 1024);
            gll16(VG + (size_t)vrow * 8192 + kvn * 2 + vmg * 16, nb + 16384 + w * 1024);
            asm volatile("s_waitcnt vmcnt(3)" ::: "memory");   // tile tI landed, tI+1 in flight
        } else {
            asm volatile("s_waitcnt vmcnt(0)" ::: "memory");
        }
        __builtin_amdgcn_sched_barrier(0);
        __builtin_amdgcn_s_barrier();

        const unsigned char* Kh_l = &KV_lds[cur][0];
        const unsigned char* Kl_l = &KV_lds[cur][8192];
        const unsigned char* V_l  = &KV_lds[cur][16384];

        f32x4 stv[2];
        __builtin_amdgcn_s_setprio(1);
#pragma unroll
        for (int tt = 0; tt < 2; tt++) {
            f32x4 shh = (f32x4){0.f, 0.f, 0.f, 0.f};
            f32x4 shl = shh, slh = shh;
            const int kbase = (tt * 16 + c) * 256;
            const int key = c & 7;
#pragma unroll
            for (int ks = 0; ks < 4; ks++) {
                const int off = kbase + (((ks * 4 + g) ^ key) * 16);
                bf16x8 kh = *(const bf16x8*)(Kh_l + off);
                bf16x8 kl = *(const bf16x8*)(Kl_l + off);
                shh = MFMA16(qhi[ks], kh, shh);
                shl = MFMA16(qhi[ks], kl, shl);
                slh = MFMA16(qlo[ks], kh, slh);
            }
            stv[tt] = shh + shl + slh;            // already exp2-domain (Q pre-scaled)
        }
        __builtin_amdgcn_s_setprio(0);

        // per-row max via DPP rotate-reduce over the 16 c-lanes (VALU-only)
        float rmax[4];
#pragma unroll
        for (int r = 0; r < 4; r++)
            rmax[r] = rowmax16(fmaxf(stv[0][r], stv[1][r]));

        bool need = (rmax[0] > mstar[0] + 65.f) || (rmax[1] > mstar[1] + 65.f) ||
                    (rmax[2] > mstar[2] + 65.f) || (rmax[3] > mstar[3] + 65.f);
        if (__any(need)) {
#pragma unroll
            for (int r = 0; r < 4; r++) {
                float nm = fmaxf(mstar[r], rmax[r]);
                float corr = exp2f(mstar[r] - nm);
                mstar[r] = nm;
                sacc[r] *= corr;
#pragma unroll
                for (int dt = 0; dt < 8; dt++) yacc[dt][r] *= corr;
            }
        }

#pragma unroll
        for (int r = 0; r < 4; r++) {
            P_lds[w][g * 4 + r][c]      = f2bf(exp2f(stv[0][r] - mstar[r]));
            P_lds[w][g * 4 + r][16 + c] = f2bf(exp2f(stv[1][r] - mstar[r]));
        }
        asm volatile("s_waitcnt lgkmcnt(0)" ::: "memory");
        __builtin_amdgcn_sched_barrier(0);

        __builtin_amdgcn_s_setprio(1);
        {
            bf16x8 pf = *(const bf16x8*)&P_lds[w][c][g * 8];
            sacc = MFMA16(pf, ones, sacc);
            const int vkey = (c >> 1) & 3;
#pragma unroll
            for (int dt = 0; dt < 8; dt++) {
                bf16x8 vf = *(const bf16x8*)(V_l + (dt * 16 + c) * 64 + ((g ^ vkey) * 16));
                yacc[dt] = MFMA16(pf, vf, yacc[dt]);
            }
        }
        __builtin_amdgcn_s_setprio(0);

        __builtin_amdgcn_sched_barrier(0);
        __builtin_amdgcn_s_barrier();              // reads of buf[cur] done before next overwrite
        cur ^= 1;
    }

    if (MODE == 0) {
        float inv[4];
#pragma unroll
        for (int r = 0; r < 4; r++) inv[r] = 1.0f / sacc[r];
#pragma unroll
        for (int dt = 0; dt < 8; dt++)
#pragma unroll
            for (int r = 0; r < 4; r++)
                Yp[((size_t)(b * NN) + q0 + g * 4 + r) * HID + dt * 16 + c] = f2bf(yacc[dt][r] * inv[r]);
    } else {
        const size_t base = (((size_t)z * NB + b) * NN + q0);
#pragma unroll
        for (int dt = 0; dt < 8; dt++)
#pragma unroll
            for (int r = 0; r < 4; r++)
                Yp[(base + g * 4 + r) * HID + dt * 16 + c] = f2bf(yacc[dt][r]);
        if (c == 0) {
#pragma unroll
            for (int r = 0; r < 4; r++) {
                Ms[base + g * 4 + r] = mstar[r];
                Ss[base + g * 4 + r] = sacc[r];
            }
        }
    }
}

// ---------------- kernel 3: output projection — bf16 MFMA + residual ----------------
template<int NS>
__global__ __launch_bounds__(256, 2)
void out_kernel(const float* __restrict__ x, const float* __restrict__ w_out,
                const unsigned short* __restrict__ Yp,
                const float* __restrict__ Ms, const float* __restrict__ Ss,
                float* __restrict__ out) {
    __shared__ __align__(16) unsigned short Yl[128][136];  // 34,816 B

    const int t = threadIdx.x;
    const int w = t >> 6, lane = t & 63;
    const int g = lane >> 4, c = lane & 15;
    const int n0 = blockIdx.x * 128;
    const int b = blockIdx.y;

    {   // stage (+combine) Y tile
        int nl = t >> 1, oh = (t & 1) * 64;
        size_t qi = (size_t)b * NN + n0 + nl;
        if (NS == 0) {
            const unsigned short* src = Yp + qi * HID + oh;
#pragma unroll
            for (int i = 0; i < 8; i++)
                *(u16x8*)&Yl[nl][oh + i * 8] = *(const u16x8*)(src + i * 8);
        } else {
            const size_t NBNN = (size_t)NB * NN;
            float m0 = Ms[qi], m1 = Ms[NBNN + qi];
            float M = fmaxf(m0, m1);
            float w0 = exp2f(m0 - M), w1 = exp2f(m1 - M);
            float S = Ss[qi] * w0 + Ss[NBNN + qi] * w1;
            float invS = 1.f / S;
            w0 *= invS; w1 *= invS;
            const unsigned short* s0 = Yp + qi * HID + oh;
            const unsigned short* s1 = Yp + (NBNN + qi) * HID + oh;
#pragma unroll
            for (int i = 0; i < 8; i++) {
                u16x8 a = *(const u16x8*)(s0 + i * 8);
                u16x8 b8 = *(const u16x8*)(s1 + i * 8);
                u16x8 vv;
#pragma unroll
                for (int j = 0; j < 8; j++)
                    vv[j] = f2bf(bf2f(a[j]) * w0 + bf2f(b8[j]) * w1);
                *(u16x8*)&Yl[nl][oh + i * 8] = vv;
            }
        }
    }
    __syncthreads();

    f32x4 acc[4][8];
#pragma unroll
    for (int mi = 0; mi < 4; mi++)
#pragma unroll
        for (int nt = 0; nt < 8; nt++) acc[mi][nt] = (f32x4){0.f, 0.f, 0.f, 0.f};

#pragma unroll
    for (int s = 0; s < 4; s++) {
        bf16x8 wf[4];
#pragma unroll
        for (int mi = 0; mi < 4; mi++) {
            const float* wp = w_out + (size_t)(w * 64 + mi * 16 + c) * HID + s * 32 + g * 8;
            float av[8];
            *(float4*)&av[0] = *(const float4*)wp;
            *(float4*)&av[4] = *(const float4*)(wp + 4);
#pragma unroll
            for (int j = 0; j < 8; j++) wf[mi][j] = (short)f2bf(av[j]);
        }
#pragma unroll
        for (int nt = 0; nt < 8; nt++) {
            bf16x8 yf = *(const bf16x8*)&Yl[nt * 16 + c][s * 32 + g * 8];
#pragma unroll
            for (int mi = 0; mi < 4; mi++) acc[mi][nt] = MFMA16(wf[mi], yf, acc[mi][nt]);
        }
    }

#pragma unroll
    for (int mi = 0; mi < 4; mi++)
#pragma unroll
        for (int nt = 0; nt < 8; nt++)
#pragma unroll
            for (int r = 0; r < 4; r++) {
                int cg = w * 64 + mi * 16 + 4 * g + r;
                size_t idx = ((size_t)(b * NC + cg)) * NN + n0 + nt * 16 + c;
                out[idx] = x[idx] + acc[mi][nt][r];
            }
}

// ---------------- launch ----------------
extern "C" void kernel_launch(void* const* d_in, const int* in_sizes, int n_in,
                              void* d_out, int out_size, void* d_ws, size_t ws_size,
                              hipStream_t stream) {
    const float* x = (const float*)d_in[0];
    const float* w_phi = (const float*)d_in[1];
    const float* w_theta = (const float*)d_in[2];
    const float* w_g = (const float*)d_in[3];
    const float* w_out = (const float*)d_in[4];
    float* out = (float*)d_out;

    const size_t BUF = (size_t)ELEMS * 2;      // 8,388,608 B per bf16 buffer
    const size_t MSB = (size_t)NB * NN * 4;    // 131,072 B per [B,N] f32 array
    if (ws_size < 6 * BUF) return;

    unsigned short* Qhi = (unsigned short*)d_ws;
    unsigned short* Qlo = (unsigned short*)((char*)d_ws + 1 * BUF);
    unsigned short* Khi = (unsigned short*)((char*)d_ws + 2 * BUF);
    unsigned short* Klo = (unsigned short*)((char*)d_ws + 3 * BUF);
    unsigned short* Vt  = (unsigned short*)((char*)d_ws + 4 * BUF);

    proj_kernel<<<dim3(32, 3, 8), 256, 0, stream>>>(x, w_theta, w_phi, w_g,
                                                    Qhi, Qlo, Khi, Klo, Vt);

    if (ws_size >= 7 * BUF + 4 * MSB) {
        // split-kv x2: 512 blocks x 512 thr = exactly 2 blocks/CU, one dispatch round
        unsigned short* Yp = (unsigned short*)((char*)d_ws + 5 * BUF);
        float* Ms = (float*)((char*)d_ws + 7 * BUF);
        float* Ss = (float*)((char*)d_ws + 7 * BUF + 2 * MSB);
        attn_kernel<1><<<dim3(512), 512, 0, stream>>>(Qhi, Qlo, Khi, Klo, Vt,
                                                      Yp, Ms, Ss, NN / 2);
        out_kernel<2><<<dim3(32, NB), 256, 0, stream>>>(x, w_out, Yp, Ms, Ss, out);
    } else {
        unsigned short* Yb = (unsigned short*)((char*)d_ws + 5 * BUF);
        attn_kernel<0><<<dim3(256), 512, 0, stream>>>(Qhi, Qlo, Khi, Klo, Vt,
                                                      Yb, nullptr, nullptr, NN);
        out_kernel<0><<<dim3(32, NB), 256, 0, stream>>>(x, w_out, Yb, nullptr, nullptr, out);
    }
}

// Round 7
// 216.458 us; speedup vs baseline: 4.2478x; 1.0780x over previous
//
#include <hip/hip_runtime.h>

// ---------------- types / helpers ----------------
typedef __attribute__((ext_vector_type(8))) short bf16x8;   // 8 bf16 (4 VGPRs) — MFMA A/B frag
typedef __attribute__((ext_vector_type(4))) float f32x4;    // 16x16 MFMA C/D frag
typedef __attribute__((ext_vector_type(16))) float f32x16;  // 32x32 MFMA C/D frag
typedef __attribute__((ext_vector_type(8))) unsigned short u16x8;

#define MFMA16(a, b, c) __builtin_amdgcn_mfma_f32_16x16x32_bf16((a), (b), (c), 0, 0, 0)
#define MFMA32(a, b, c) __builtin_amdgcn_mfma_f32_32x32x16_bf16((a), (b), (c), 0, 0, 0)

__device__ __forceinline__ unsigned short f2bf(float v) {
    unsigned u = __float_as_uint(v);
    return (unsigned short)((u + 0x7fffu + ((u >> 16) & 1u)) >> 16);  // RN
}
__device__ __forceinline__ float bf2f(unsigned short h) {
    return __uint_as_float(((unsigned)h) << 16);
}
// async global->LDS DMA, 16B/lane; LDS dest = base + lane*16 (hardware), global src per-lane.
__device__ __forceinline__ void gll16(const void* g, void* l) {
    __builtin_amdgcn_global_load_lds(
        (const __attribute__((address_space(1))) unsigned int*)g,
        (__attribute__((address_space(3))) unsigned int*)l, 16, 0, 0);
}
// pack two f32 -> one u32 of 2 bf16 (lo = src0, hi = src1)
__device__ __forceinline__ unsigned cvtpk(float lo, float hi) {
    unsigned r;
    asm("v_cvt_pk_bf16_f32 %0, %1, %2" : "=v"(r) : "v"(lo), "v"(hi));
    return r;
}
// swap lanes[32:63] of a with lanes[0:31] of b (in place)
#define PSWAP(a, b) asm volatile("v_permlane32_swap_b32 %0, %1" : "+v"(a), "+v"(b))

__device__ __forceinline__ f32x16 zero16() {
    f32x16 z;
#pragma unroll
    for (int j = 0; j < 16; j++) z[j] = 0.f;
    return z;
}

// B=8, C=256, H=W=64, N=4096, HID=128
#define NB 8
#define NC 256
#define NN 4096
#define HID 128
#define ELEMS (NB * NN * HID)            // 4,194,304 per [B,N,128] bf16 buffer

// ---------------- kernel 1: projections — hi/lo bf16 MFMA (unchanged) ----------------
__global__ __launch_bounds__(256, 2)
void proj_kernel(const float* __restrict__ x,
                 const float* __restrict__ w_theta,
                 const float* __restrict__ w_phi,
                 const float* __restrict__ w_g,
                 unsigned short* __restrict__ Qhi, unsigned short* __restrict__ Qlo,
                 unsigned short* __restrict__ Khi, unsigned short* __restrict__ Klo,
                 unsigned short* __restrict__ Vt) {
    __shared__ __align__(16) unsigned char LdsRaw[128 * 65 * 4];  // 33,280 B (union)
    float (*xs)[129] = reinterpret_cast<float(*)[129]>(LdsRaw);
    unsigned int (*Tb)[65] = reinterpret_cast<unsigned int(*)[65]>(LdsRaw);

    const int t = threadIdx.x;
    const int w = t >> 6, lane = t & 63;
    const int g = lane >> 4, c = lane & 15;
    const int n0 = blockIdx.x * 128;
    const int which = blockIdx.y;
    const int b = blockIdx.z;
    const float* wsel = (which == 0) ? w_theta : ((which == 1) ? w_phi : w_g);

    f32x4 acc[2][8];
#pragma unroll
    for (int mi = 0; mi < 2; mi++)
#pragma unroll
        for (int nt = 0; nt < 8; nt++) acc[mi][nt] = (f32x4){0.f, 0.f, 0.f, 0.f};

    const int srow = w * 16 + (lane >> 2);
    const int snq = (lane & 3) * 32;

    for (int k0 = 0; k0 < NC; k0 += 64) {
        __syncthreads();
        {
            const float* src = x + ((size_t)(b * NC + k0 + srow)) * NN + n0 + snq;
            float4 v[8];
#pragma unroll
            for (int u = 0; u < 8; u++) v[u] = *(const float4*)(src + 4 * u);
#pragma unroll
            for (int u = 0; u < 8; u++) {
                xs[srow][snq + 4 * u + 0] = v[u].x;
                xs[srow][snq + 4 * u + 1] = v[u].y;
                xs[srow][snq + 4 * u + 2] = v[u].z;
                xs[srow][snq + 4 * u + 3] = v[u].w;
            }
        }
        __syncthreads();

#pragma unroll
        for (int s = 0; s < 2; s++) {
            bf16x8 wh[2], wl[2];
#pragma unroll
            for (int mi = 0; mi < 2; mi++) {
                const float* wp = wsel + (size_t)(w * 32 + mi * 16 + c) * NC + k0 + s * 32 + g * 8;
                float av[8];
                *(float4*)&av[0] = *(const float4*)wp;
                *(float4*)&av[4] = *(const float4*)(wp + 4);
#pragma unroll
                for (int j = 0; j < 8; j++) {
                    unsigned short hh = f2bf(av[j]);
                    wh[mi][j] = (short)hh;
                    if (which < 2) wl[mi][j] = (short)f2bf(av[j] - bf2f(hh));
                }
            }
#pragma unroll
            for (int nt = 0; nt < 8; nt++) {
                float bv[8];
#pragma unroll
                for (int j = 0; j < 8; j++) bv[j] = xs[s * 32 + g * 8 + j][nt * 16 + c];
                bf16x8 xh, xl;
#pragma unroll
                for (int j = 0; j < 8; j++) {
                    unsigned short hh = f2bf(bv[j]);
                    xh[j] = (short)hh;
                    if (which < 2) xl[j] = (short)f2bf(bv[j] - bf2f(hh));
                }
#pragma unroll
                for (int mi = 0; mi < 2; mi++) {
                    acc[mi][nt] = MFMA16(wh[mi], xh, acc[mi][nt]);
                    if (which < 2) {
                        acc[mi][nt] = MFMA16(wh[mi], xl, acc[mi][nt]);
                        acc[mi][nt] = MFMA16(wl[mi], xh, acc[mi][nt]);
                    }
                }
            }
        }
    }

    if (which == 2) {
#pragma unroll
        for (int mi = 0; mi < 2; mi++)
#pragma unroll
            for (int nt = 0; nt < 8; nt++)
#pragma unroll
                for (int r = 0; r < 4; r++) {
                    int o = w * 32 + mi * 16 + 4 * g + r;
                    Vt[((size_t)(b * HID + o)) * NN + n0 + nt * 16 + c] = f2bf(acc[mi][nt][r]);
                }
    } else {
        unsigned short* dh = (which == 0) ? Qhi : Khi;
        unsigned short* dl = (which == 0) ? Qlo : Klo;
        const float qscale = (which == 0) ? 16.32223142f : 1.0f;  // sqrt(128)*log2(e) folded into theta
        for (int h = 0; h < 2; h++) {
            __syncthreads();
#pragma unroll
            for (int mi = 0; mi < 2; mi++)
#pragma unroll
                for (int q2 = 0; q2 < 4; q2++) {
                    int nt = h * 4 + q2;
#pragma unroll
                    for (int r = 0; r < 4; r++) {
                        float v = acc[mi][nt][r] * qscale;
                        unsigned short hi = f2bf(v);
                        unsigned short lo = f2bf(v - bf2f(hi));
                        Tb[w * 32 + mi * 16 + 4 * g + r][q2 * 16 + c] = (((unsigned)hi) << 16) | lo;
                    }
                }
            __syncthreads();
            {
                int nl = t & 63;
                int og = (t >> 6) * 32;
                int n = n0 + h * 64 + nl;
                u16x8 vh[4], vl[4];
#pragma unroll
                for (int k = 0; k < 32; k++) {
                    unsigned u = Tb[og + k][nl];
                    vh[k >> 3][k & 7] = (unsigned short)(u >> 16);
                    vl[k >> 3][k & 7] = (unsigned short)(u & 0xffffu);
                }
                size_t base = ((size_t)(b * NN + n)) * HID + og;
#pragma unroll
                for (int q = 0; q < 4; q++) {
                    *(u16x8*)(dh + base + q * 8) = vh[q];
                    *(u16x8*)(dl + base + q * 8) = vl[q];
                }
            }
        }
    }
}

// ---------------- kernel 2: flash attention v5 — 32x32 MFMA, swapped QK^T, in-reg P ----------------
// 256 thr / 4 waves; wave owns 32 q-rows. KVBLK=32, double-buffered LDS (48 KB), 24 gll16
// stage instrs (6/wave), vmcnt(6). Swapped QK^T mfma(K,Q): lane's P is lane-local per
// q=lane&31 -> softmax has ONE cross-lane op (shfl_xor 32). P -> PV A-frag via
// 8 cvt_pk + 4 v_permlane32_swap (no LDS roundtrip). mstar/sacc per-lane scalars.
template<int MODE>   // 0: single-split, normalize+write Y; 1: split-kv x2, write partials
__global__ __launch_bounds__(256, 2)
void attn_kernel(const unsigned short* __restrict__ Qhi, const unsigned short* __restrict__ Qlo,
                 const unsigned short* __restrict__ Khi, const unsigned short* __restrict__ Klo,
                 const unsigned short* __restrict__ Vt,
                 unsigned short* __restrict__ Yp, float* __restrict__ Ms, float* __restrict__ Ss,
                 int kv_len) {
    __shared__ __align__(16) unsigned char KV_lds[2][24576];   // Khi[0,8K) Klo[8K,16K) V[16K,24K)

    const int t = threadIdx.x;
    const int w = t >> 6, lane = t & 63;
    const int l31 = lane & 31, hi = lane >> 5;
    const int bid = blockIdx.x;
    const int b = bid & 7;                       // batch -> XCD pin
    const int z = (MODE == 1) ? ((bid >> 3) & 1) : 0;
    const int qx = (MODE == 1) ? (bid >> 4) : (bid >> 3);
    const int q0 = qx * 128 + w * 32;

    const int kvb = z * kv_len;
    const char* KhG = (const char*)(Khi + ((size_t)(b * NN) + kvb) * HID);
    const char* KlG = (const char*)(Klo + ((size_t)(b * NN) + kvb) * HID);
    const char* VG  = (const char*)(Vt + ((size_t)(b * HID)) * NN + kvb);

    // staging lane constants: wave w handles slots {2w, 2w+1} of each of Khi/Klo/V
    const int si0 = w * 2, si1 = w * 2 + 1;
    const int krow0 = si0 * 4 + (lane >> 4), krow1 = si1 * 4 + (lane >> 4);  // K rows 0..31
    const int kq = lane & 15;
    const int kqg0 = kq ^ (krow0 & 15), kqg1 = kq ^ (krow1 & 15);            // 16-chunk swizzle
    const int vrow0 = si0 * 16 + (lane >> 2), vrow1 = si1 * 16 + (lane >> 2); // V rows 0..127
    const int vm = lane & 3;
    const int vmg0 = vm ^ ((vrow0 >> 1) & 3), vmg1 = vm ^ ((vrow1 >> 1) & 3);

#define STAGE(buf, kvoff)                                                                        \
    do {                                                                                         \
        gll16(KhG + (size_t)((kvoff) + krow0) * 256 + kqg0 * 16, (buf) + si0 * 1024);            \
        gll16(KhG + (size_t)((kvoff) + krow1) * 256 + kqg1 * 16, (buf) + si1 * 1024);            \
        gll16(KlG + (size_t)((kvoff) + krow0) * 256 + kqg0 * 16, (buf) + 8192 + si0 * 1024);     \
        gll16(KlG + (size_t)((kvoff) + krow1) * 256 + kqg1 * 16, (buf) + 8192 + si1 * 1024);     \
        gll16(VG + (size_t)vrow0 * 8192 + (size_t)(kvoff) * 2 + vmg0 * 16, (buf) + 16384 + si0 * 1024); \
        gll16(VG + (size_t)vrow1 * 8192 + (size_t)(kvoff) * 2 + vmg1 * 16, (buf) + 16384 + si1 * 1024); \
    } while (0)

    STAGE(&KV_lds[0][0], 0);   // prologue: tile 0 -> buf 0

    // Q fragments (B-operand, 32 rows): lane reads Q[q0+l31][k = 16s + hi*8 .. +7]
    bf16x8 qh[8], ql[8];
    {
        const unsigned short* qp = Qhi + ((size_t)(b * NN) + q0 + l31) * HID + hi * 8;
        const unsigned short* qp2 = Qlo + ((size_t)(b * NN) + q0 + l31) * HID + hi * 8;
#pragma unroll
        for (int s = 0; s < 8; s++) {
            qh[s] = *(const bf16x8*)(qp + s * 16);
            ql[s] = *(const bf16x8*)(qp2 + s * 16);
        }
    }

    float mstar = -3.0e38f, sacc = 0.f;   // per-lane, q = l31 (exp2-domain; Q pre-scaled)
    f32x16 yacc[4];
#pragma unroll
    for (int dt = 0; dt < 4; dt++) yacc[dt] = zero16();

    const int ntl = kv_len >> 5;   // KVBLK=32
    int cur = 0;
    const int krbase = l31 * 256;
    const int kkey = l31 & 15;
    const int vkey = (l31 >> 1) & 3;

    for (int tI = 0; tI < ntl; ++tI) {
        if (tI + 1 < ntl) {
            STAGE(&KV_lds[cur ^ 1][0], (tI + 1) * 32);
            asm volatile("s_waitcnt vmcnt(6)" ::: "memory");   // tile tI landed, tI+1 in flight
        } else {
            asm volatile("s_waitcnt vmcnt(0)" ::: "memory");
        }
        __builtin_amdgcn_sched_barrier(0);
        __builtin_amdgcn_s_barrier();

        const unsigned char* Kh_l = &KV_lds[cur][0];
        const unsigned char* Kl_l = &KV_lds[cur][8192];
        const unsigned char* V_l  = &KV_lds[cur][16384];

        // ---- swapped QK^T: S^T = K * Q (3-term hi/lo), D[k-row][q-col] ----
        f32x16 shh = zero16(), sa = zero16(), sb = zero16();
        __builtin_amdgcn_s_setprio(1);
#pragma unroll
        for (int s = 0; s < 8; s++) {
            const int off = krbase + (((2 * s + hi) ^ kkey) * 16);
            bf16x8 kh = *(const bf16x8*)(Kh_l + off);
            bf16x8 kl = *(const bf16x8*)(Kl_l + off);
            shh = MFMA32(kh, qh[s], shh);
            sa  = MFMA32(kl, qh[s], sa);
            sb  = MFMA32(kh, ql[s], sb);
        }
        __builtin_amdgcn_s_setprio(0);
        f32x16 stv = shh + sa + sb;   // lane: q=l31; k = (r&3)+8*(r>>2)+4*hi per reg r

        // ---- softmax (lane-local; one cross-lane max) ----
        float m = stv[0];
#pragma unroll
        for (int r = 1; r < 16; r++) m = fmaxf(m, stv[r]);
        m = fmaxf(m, __shfl_xor(m, 32));

        if (__any(m > mstar + 65.f)) {         // defer-max: rescale only on headroom breach
            float nm = fmaxf(mstar, m);
            float corr = exp2f(mstar - nm);    // first tile: ~0
            mstar = nm;
            sacc *= corr;
            float cr[16];
#pragma unroll
            for (int r = 0; r < 16; r++)
                cr[r] = __shfl(corr, (r & 3) + 8 * (r >> 2) + 4 * hi);  // corr of q-row of reg r
#pragma unroll
            for (int dt = 0; dt < 4; dt++)
#pragma unroll
                for (int r = 0; r < 16; r++) yacc[dt][r] *= cr[r];
        }

        float p[16];
#pragma unroll
        for (int r = 0; r < 16; r++) p[r] = exp2f(stv[r] - mstar);
        float ls = 0.f;
#pragma unroll
        for (int r = 0; r < 16; r++) ls += p[r];
        sacc += ls;

        // ---- P -> PV A-frag in registers: 8 cvt_pk + 4 permlane32_swap ----
        unsigned X0 = cvtpk(p[0], p[1]),   X1 = cvtpk(p[2], p[3]);
        unsigned X2 = cvtpk(p[4], p[5]),   X3 = cvtpk(p[6], p[7]);
        unsigned X4 = cvtpk(p[8], p[9]),   X5 = cvtpk(p[10], p[11]);
        unsigned X6 = cvtpk(p[12], p[13]), X7 = cvtpk(p[14], p[15]);
        PSWAP(X0, X2); PSWAP(X1, X3);      // k 0..15 frag (s=0)
        PSWAP(X4, X6); PSWAP(X5, X7);      // k 16..31 frag (s=1)
        union { unsigned u[4]; bf16x8 v; } pa, pb;
        pa.u[0] = X0; pa.u[1] = X1; pa.u[2] = X2; pa.u[3] = X3;
        pb.u[0] = X4; pb.u[1] = X5; pb.u[2] = X6; pb.u[3] = X7;
        bf16x8 pf0 = pa.v, pf1 = pb.v;

        // ---- PV: Y += P * V ----
        __builtin_amdgcn_s_setprio(1);
#pragma unroll
        for (int dt = 0; dt < 4; dt++) {
            const int vbase = (dt * 32 + l31) * 64;
            bf16x8 v0 = *(const bf16x8*)(V_l + vbase + ((hi ^ vkey) * 16));
            bf16x8 v1 = *(const bf16x8*)(V_l + vbase + (((2 + hi) ^ vkey) * 16));
            yacc[dt] = MFMA32(pf0, v0, yacc[dt]);
            yacc[dt] = MFMA32(pf1, v1, yacc[dt]);
        }
        __builtin_amdgcn_s_setprio(0);

        __builtin_amdgcn_sched_barrier(0);
        __builtin_amdgcn_s_barrier();          // buf[cur] reads done before next overwrite
        cur ^= 1;
    }

    float stot = sacc + __shfl_xor(sacc, 32);  // total row-sum for q=l31

    if (MODE == 0) {
        float inv = 1.0f / stot;
        float ivr[16];
#pragma unroll
        for (int r = 0; r < 16; r++)
            ivr[r] = __shfl(inv, (r & 3) + 8 * (r >> 2) + 4 * hi);
        const size_t obase = (size_t)(b * NN) + q0;
#pragma unroll
        for (int dt = 0; dt < 4; dt++)
#pragma unroll
            for (int r = 0; r < 16; r++) {
                int q = (r & 3) + 8 * (r >> 2) + 4 * hi;
                Yp[(obase + q) * HID + dt * 32 + l31] = f2bf(yacc[dt][r] * ivr[r]);
            }
    } else {
        const size_t base = (((size_t)z * NB + b) * NN + q0);
#pragma unroll
        for (int dt = 0; dt < 4; dt++)
#pragma unroll
            for (int r = 0; r < 16; r++) {
                int q = (r & 3) + 8 * (r >> 2) + 4 * hi;
                Yp[(base + q) * HID + dt * 32 + l31] = f2bf(yacc[dt][r]);
            }
        if (hi == 0) {
            Ms[base + l31] = mstar;
            Ss[base + l31] = stot;
        }
    }
#undef STAGE
}

// ---------------- kernel 3: output projection — bf16 MFMA + residual (unchanged) ----------------
template<int NS>
__global__ __launch_bounds__(256, 2)
void out_kernel(const float* __restrict__ x, const float* __restrict__ w_out,
                const unsigned short* __restrict__ Yp,
                const float* __restrict__ Ms, const float* __restrict__ Ss,
                float* __restrict__ out) {
    __shared__ __align__(16) unsigned short Yl[128][136];  // 34,816 B

    const int t = threadIdx.x;
    const int w = t >> 6, lane = t & 63;
    const int g = lane >> 4, c = lane & 15;
    const int n0 = blockIdx.x * 128;
    const int b = blockIdx.y;

    {   // stage (+combine) Y tile
        int nl = t >> 1, oh = (t & 1) * 64;
        size_t qi = (size_t)b * NN + n0 + nl;
        if (NS == 0) {
            const unsigned short* src = Yp + qi * HID + oh;
#pragma unroll
            for (int i = 0; i < 8; i++)
                *(u16x8*)&Yl[nl][oh + i * 8] = *(const u16x8*)(src + i * 8);
        } else {
            const size_t NBNN = (size_t)NB * NN;
            float m0 = Ms[qi], m1 = Ms[NBNN + qi];
            float M = fmaxf(m0, m1);
            float w0 = exp2f(m0 - M), w1 = exp2f(m1 - M);
            float S = Ss[qi] * w0 + Ss[NBNN + qi] * w1;
            float invS = 1.f / S;
            w0 *= invS; w1 *= invS;
            const unsigned short* s0 = Yp + qi * HID + oh;
            const unsigned short* s1 = Yp + (NBNN + qi) * HID + oh;
#pragma unroll
            for (int i = 0; i < 8; i++) {
                u16x8 a = *(const u16x8*)(s0 + i * 8);
                u16x8 b8 = *(const u16x8*)(s1 + i * 8);
                u16x8 vv;
#pragma unroll
                for (int j = 0; j < 8; j++)
                    vv[j] = f2bf(bf2f(a[j]) * w0 + bf2f(b8[j]) * w1);
                *(u16x8*)&Yl[nl][oh + i * 8] = vv;
            }
        }
    }
    __syncthreads();

    f32x4 acc[4][8];
#pragma unroll
    for (int mi = 0; mi < 4; mi++)
#pragma unroll
        for (int nt = 0; nt < 8; nt++) acc[mi][nt] = (f32x4){0.f, 0.f, 0.f, 0.f};

#pragma unroll
    for (int s = 0; s < 4; s++) {
        bf16x8 wf[4];
#pragma unroll
        for (int mi = 0; mi < 4; mi++) {
            const float* wp = w_out + (size_t)(w * 64 + mi * 16 + c) * HID + s * 32 + g * 8;
            float av[8];
            *(float4*)&av[0] = *(const float4*)wp;
            *(float4*)&av[4] = *(const float4*)(wp + 4);
#pragma unroll
            for (int j = 0; j < 8; j++) wf[mi][j] = (short)f2bf(av[j]);
        }
#pragma unroll
        for (int nt = 0; nt < 8; nt++) {
            bf16x8 yf = *(const bf16x8*)&Yl[nt * 16 + c][s * 32 + g * 8];
#pragma unroll
            for (int mi = 0; mi < 4; mi++) acc[mi][nt] = MFMA16(wf[mi], yf, acc[mi][nt]);
        }
    }

#pragma unroll
    for (int mi = 0; mi < 4; mi++)
#pragma unroll
        for (int nt = 0; nt < 8; nt++)
#pragma unroll
            for (int r = 0; r < 4; r++) {
                int cg = w * 64 + mi * 16 + 4 * g + r;
                size_t idx = ((size_t)(b * NC + cg)) * NN + n0 + nt * 16 + c;
                out[idx] = x[idx] + acc[mi][nt][r];
            }
}

// ---------------- launch ----------------
extern "C" void kernel_launch(void* const* d_in, const int* in_sizes, int n_in,
                              void* d_out, int out_size, void* d_ws, size_t ws_size,
                              hipStream_t stream) {
    const float* x = (const float*)d_in[0];
    const float* w_phi = (const float*)d_in[1];
    const float* w_theta = (const float*)d_in[2];
    const float* w_g = (const float*)d_in[3];
    const float* w_out = (const float*)d_in[4];
    float* out = (float*)d_out;

    const size_t BUF = (size_t)ELEMS * 2;      // 8,388,608 B per bf16 buffer
    const size_t MSB = (size_t)NB * NN * 4;    // 131,072 B per [B,N] f32 array
    if (ws_size < 6 * BUF) return;

    unsigned short* Qhi = (unsigned short*)d_ws;
    unsigned short* Qlo = (unsigned short*)((char*)d_ws + 1 * BUF);
    unsigned short* Khi = (unsigned short*)((char*)d_ws + 2 * BUF);
    unsigned short* Klo = (unsigned short*)((char*)d_ws + 3 * BUF);
    unsigned short* Vt  = (unsigned short*)((char*)d_ws + 4 * BUF);

    proj_kernel<<<dim3(32, 3, 8), 256, 0, stream>>>(x, w_theta, w_phi, w_g,
                                                    Qhi, Qlo, Khi, Klo, Vt);

    if (ws_size >= 7 * BUF + 4 * MSB) {
        // split-kv x2: 512 blocks x 256 thr, 2 blocks/CU, one dispatch round
        unsigned short* Yp = (unsigned short*)((char*)d_ws + 5 * BUF);
        float* Ms = (float*)((char*)d_ws + 7 * BUF);
        float* Ss = (float*)((char*)d_ws + 7 * BUF + 2 * MSB);
        attn_kernel<1><<<dim3(512), 256, 0, stream>>>(Qhi, Qlo, Khi, Klo, Vt,
                                                      Yp, Ms, Ss, NN / 2);
        out_kernel<2><<<dim3(32, NB), 256, 0, stream>>>(x, w_out, Yp, Ms, Ss, out);
    } else {
        unsigned short* Yb = (unsigned short*)((char*)d_ws + 5 * BUF);
        attn_kernel<0><<<dim3(256), 256, 0, stream>>>(Qhi, Qlo, Khi, Klo, Vt,
                                                      Yb, nullptr, nullptr, NN);
        out_kernel<0><<<dim3(32, NB), 256, 0, stream>>>(x, w_out, Yb, nullptr, nullptr, out);
    }
}